// Round 7
// baseline (430.385 us; speedup 1.0000x reference)
//
#include <hip/hip_runtime.h>
#include <hip/hip_bf16.h>

// AttnBlock2d: GN -> q/k/v 1x1conv -> softmax(q^T k / sqrt(C)) -> v@alpha -> proj -> +x
// B=8, C=256, H*W=4096. bf16 MFMA, fp32 accum.
// R7: R6 + restored prefetch-under-compute: KVBLK=32 double-buffered (64.5KB LDS,
// 2 blocks/CU, 2 waves/SIMD), loop = {issue stage(t+1) -> compute(t) -> barrier} so
// staging latency hides under MFMA+softmax. QK chain split into 2 independent
// 8-deep MFMA chains. K/V granule-planar global layouts unchanged (linear LDS reads).

typedef unsigned int u32;
typedef unsigned short u16;
typedef __bf16 bf16x8 __attribute__((ext_vector_type(8)));
typedef float f32x4 __attribute__((ext_vector_type(4)));
typedef float f32x16 __attribute__((ext_vector_type(16)));

#define GAS __attribute__((address_space(1)))
#define LAS __attribute__((address_space(3)))

__device__ __forceinline__ u16 f2bf(float f) {
  union { float f; u32 u; } v; v.f = f;
  return (u16)((v.u + 0x7fffu + ((v.u >> 16) & 1u)) >> 16);
}

__device__ __forceinline__ f32x4 mfma16(bf16x8 a, bf16x8 b, f32x4 c) {
  return __builtin_amdgcn_mfma_f32_16x16x32_bf16(a, b, c, 0, 0, 0);
}
__device__ __forceinline__ f32x16 mfma32(bf16x8 a, bf16x8 b, f32x16 c) {
  return __builtin_amdgcn_mfma_f32_32x32x16_bf16(a, b, c, 0, 0, 0);
}

// Stage [ROWS][ROWB bytes] row-major bf16 tile into LDS via global_load_lds,
// XOR swizzle on the SOURCE side (linear dest + inverse-swz source). (GEMMs only.)
template<int ROWB, int MASK, int ITERS, int NT>
__device__ __forceinline__ void stage_swz(u16* lds, const u16* g, int ldg, int tid) {
#pragma unroll
  for (int it = 0; it < ITERS; ++it) {
    int idx = it * NT + tid;
    int off = idx * 16;
    int row = off / ROWB;
    int slot = off % ROWB;
    int sem = slot ^ ((row & MASK) << 4);
    const u16* src = g + (long)row * ldg + (sem >> 1);
    u16* dst = lds + (long)(idx & ~63) * 8;
    __builtin_amdgcn_global_load_lds((const GAS u32*)src, (LAS u32*)dst, 16, 0, 0);
  }
}

// Stage a fully-contiguous region: linear global -> linear LDS, coalesced.
template<int ITERS, int NT>
__device__ __forceinline__ void stage_lin(u16* lds, const u16* g, int tid) {
#pragma unroll
  for (int it = 0; it < ITERS; ++it) {
    int idx = it * NT + tid;
    const u16* src = g + (long)idx * 8;
    u16* dst = lds + (long)(idx & ~63) * 8;
    __builtin_amdgcn_global_load_lds((const GAS u32*)src, (LAS u32*)dst, 16, 0, 0);
  }
}

template<int ROWB, int MASK>
__device__ __forceinline__ bf16x8 ldfrag(const u16* lds, int row, int kbyte) {
  int off = row * ROWB + (kbyte ^ ((row & MASK) << 4));
  return *(const bf16x8*)((const char*)lds + off);
}

// ---------------- weight fp32 -> bf16 ----------------
__global__ __launch_bounds__(256) void convert_w(
    const float* __restrict__ w0, const float* __restrict__ w1,
    const float* __restrict__ w2, const float* __restrict__ w3,
    u16* __restrict__ out) {
  int i = blockIdx.x * 256 + threadIdx.x;
  int seg = i >> 16, idx = i & 65535;
  const float* w = seg == 0 ? w0 : seg == 1 ? w1 : seg == 2 ? w2 : w3;
  out[i] = f2bf(w[idx]);
}

// ---------------- GroupNorm: x [B][C][N] fp32 -> h_t [B][N][C] bf16 ----------------
__global__ __launch_bounds__(256) void gn_kernel(
    const float* __restrict__ x, const float* __restrict__ gamma,
    const float* __restrict__ beta, u16* __restrict__ ht) {
  int tid = threadIdx.x;
  int b = blockIdx.x >> 4;
  int grp = blockIdx.x & 15;
  const float* xg = x + ((long)b * 256 + grp * 16) * 4096;

  float s = 0.f, ss = 0.f;
  const float4* x4 = (const float4*)xg;
#pragma unroll 4
  for (int it = 0; it < 64; ++it) {
    float4 v = x4[it * 256 + tid];
    s += v.x + v.y + v.z + v.w;
    ss += v.x * v.x + v.y * v.y + v.z * v.z + v.w * v.w;
  }
#pragma unroll
  for (int d = 1; d < 64; d <<= 1) {
    s += __shfl_xor(s, d);
    ss += __shfl_xor(ss, d);
  }
  __shared__ float red[10];
  int lane = tid & 63, wave = tid >> 6;
  if (lane == 0) { red[wave] = s; red[4 + wave] = ss; }
  __syncthreads();
  if (tid == 0) {
    float S = red[0] + red[1] + red[2] + red[3];
    float SS = red[4] + red[5] + red[6] + red[7];
    float mean = S * (1.f / 65536.f);
    float var = SS * (1.f / 65536.f) - mean * mean;
    red[8] = mean;
    red[9] = rsqrtf(var + 1e-6f);
  }
  __syncthreads();
  float mean = red[8], rstd = red[9];

  float a[16], bb[16];
#pragma unroll
  for (int c = 0; c < 16; ++c) {
    float gm = gamma[grp * 16 + c];
    float bt = beta[grp * 16 + c];
    a[c] = gm * rstd;
    bb[c] = bt - mean * a[c];
  }
  u16* hb = ht + (long)b * 4096 * 256 + grp * 16;
  for (int it = 0; it < 16; ++it) {
    int n = it * 256 + tid;
    __align__(16) u16 tmp[16];
#pragma unroll
    for (int c = 0; c < 16; ++c)
      tmp[c] = f2bf(xg[(long)c * 4096 + n] * a[c] + bb[c]);
    u16* dst = hb + (long)n * 256;
    ((uint4*)dst)[0] = ((uint4*)tmp)[0];
    ((uint4*)dst)[1] = ((uint4*)tmp)[1];
  }
}

// ---------------- fused QKV GEMM ----------------
// q_t out [pos][o] bf16 (pre-scaled by C^-0.5*log2e).
// k out granule-planar: kgp[b][jt=pos/32][cg=o/8][j=pos&31][o&7].
// v out granule-planar: vgp[b][jt=pos/32][g=(pos/8)&3][o][pos&7].
__global__ __launch_bounds__(256) void gemm_qkv(
    const u16* __restrict__ ht, const u16* __restrict__ wbf,
    u16* __restrict__ qtb, u16* __restrict__ ktb, u16* __restrict__ vcb,
    const float* __restrict__ bq, const float* __restrict__ bk,
    const float* __restrict__ bv) {
  __shared__ __align__(16) u16 as[64 * 64];
  __shared__ __align__(16) u16 bqs[64 * 64];
  __shared__ __align__(16) u16 bks[64 * 64];
  __shared__ __align__(16) u16 bvs[64 * 64];
  int tid = threadIdx.x;
  int lane = tid & 63, wave = tid >> 6;
  int g = lane >> 4, lr = lane & 15;
  int wm = wave >> 1, wn = wave & 1;
  const u16* Ab = ht + (long)blockIdx.x * 64 * 256;
  const u16* Wq = wbf + (long)blockIdx.y * 64 * 256;

  f32x4 zero = {0.f, 0.f, 0.f, 0.f};
  f32x4 acc[3][2][2];
#pragma unroll
  for (int w = 0; w < 3; ++w)
#pragma unroll
    for (int i = 0; i < 2; ++i)
#pragma unroll
      for (int j = 0; j < 2; ++j) acc[w][i][j] = zero;

  for (int k0 = 0; k0 < 256; k0 += 64) {
    stage_swz<128, 7, 2, 256>(as, Ab + k0, 256, tid);
    stage_swz<128, 7, 2, 256>(bqs, Wq + k0, 256, tid);
    stage_swz<128, 7, 2, 256>(bks, Wq + 65536 + k0, 256, tid);
    stage_swz<128, 7, 2, 256>(bvs, Wq + 131072 + k0, 256, tid);
    __syncthreads();
#pragma unroll
    for (int ks = 0; ks < 2; ++ks) {
      int kb = ks * 64 + g * 16;
      bf16x8 a0 = ldfrag<128, 7>(as, wm * 32 + lr, kb);
      bf16x8 a1 = ldfrag<128, 7>(as, wm * 32 + 16 + lr, kb);
      __builtin_amdgcn_s_setprio(1);
      {
        bf16x8 b0 = ldfrag<128, 7>(bqs, wn * 32 + lr, kb);
        bf16x8 b1 = ldfrag<128, 7>(bqs, wn * 32 + 16 + lr, kb);
        acc[0][0][0] = mfma16(a0, b0, acc[0][0][0]);
        acc[0][0][1] = mfma16(a0, b1, acc[0][0][1]);
        acc[0][1][0] = mfma16(a1, b0, acc[0][1][0]);
        acc[0][1][1] = mfma16(a1, b1, acc[0][1][1]);
      }
      {
        bf16x8 b0 = ldfrag<128, 7>(bks, wn * 32 + lr, kb);
        bf16x8 b1 = ldfrag<128, 7>(bks, wn * 32 + 16 + lr, kb);
        acc[1][0][0] = mfma16(a0, b0, acc[1][0][0]);
        acc[1][0][1] = mfma16(a0, b1, acc[1][0][1]);
        acc[1][1][0] = mfma16(a1, b0, acc[1][1][0]);
        acc[1][1][1] = mfma16(a1, b1, acc[1][1][1]);
      }
      {
        bf16x8 b0 = ldfrag<128, 7>(bvs, wn * 32 + lr, kb);
        bf16x8 b1 = ldfrag<128, 7>(bvs, wn * 32 + 16 + lr, kb);
        acc[2][0][0] = mfma16(a0, b0, acc[2][0][0]);
        acc[2][0][1] = mfma16(a0, b1, acc[2][0][1]);
        acc[2][1][0] = mfma16(a1, b0, acc[2][1][0]);
        acc[2][1][1] = mfma16(a1, b1, acc[2][1][1]);
      }
      __builtin_amdgcn_s_setprio(0);
    }
    __syncthreads();
  }

  const float QSC = 0.0625f * 1.44269504f;   // C^-0.5 * log2(e), folded into q
  int mb = blockIdx.x * 64 + wm * 32;
  int nb = blockIdx.y * 64 + wn * 32;
  int b_ = mb >> 12;
  int posb = mb & 4095;
#pragma unroll
  for (int mi = 0; mi < 2; ++mi)
#pragma unroll
    for (int ni = 0; ni < 2; ++ni) {
      int n = nb + ni * 16 + lr;
      int pos0 = posb + mi * 16 + 4 * g;          // rows pos0..pos0+3 (same 32-tile)
      int jt = pos0 >> 5, jj = pos0 & 31;
      long kbase = (long)b_ * 1048576 + (long)jt * 8192 + (n >> 3) * 256 + jj * 8 + (n & 7);
      __align__(8) u16 v4[4];
#pragma unroll
      for (int e = 0; e < 4; ++e) {
        int m = mb + mi * 16 + 4 * g + e;
        long addr = (long)m * 256 + n;
        qtb[addr] = f2bf((acc[0][mi][ni][e] + bq[n]) * QSC);
        ktb[kbase + e * 8] = f2bf(acc[1][mi][ni][e] + bk[n]);
        v4[e] = f2bf(acc[2][mi][ni][e] + bv[n]);
      }
      int gg = (pos0 >> 3) & 3, js = pos0 & 7;
      *(uint2*)(vcb + (long)b_ * 1048576 + (long)jt * 8192 + gg * 2048 + n * 8 + js)
          = *(uint2*)v4;
    }
}

// ---------------- proj GEMM + residual: D[m=o][n=pos] fp32 ----------------
__global__ __launch_bounds__(256) void gemm_proj(
    const u16* __restrict__ A, const u16* __restrict__ Bt,
    float* __restrict__ outp, const float* __restrict__ bias,
    const float* __restrict__ resid) {
  __shared__ __align__(16) u16 as[64 * 64];
  __shared__ __align__(16) u16 bs[64 * 64];
  int tid = threadIdx.x;
  int lane = tid & 63, wave = tid >> 6;
  int g = lane >> 4, lr = lane & 15;
  int wm = wave >> 1, wn = wave & 1;
  int z = blockIdx.z;
  const u16* Ab = A + (long)blockIdx.x * 64 * 256;
  const u16* Bb = Bt + (long)z * 4096 * 256 + (long)blockIdx.y * 64 * 256;

  f32x4 zero = {0.f, 0.f, 0.f, 0.f};
  f32x4 acc[2][2];
#pragma unroll
  for (int i = 0; i < 2; ++i)
#pragma unroll
    for (int j = 0; j < 2; ++j) acc[i][j] = zero;

  for (int k0 = 0; k0 < 256; k0 += 64) {
    stage_swz<128, 7, 2, 256>(as, Ab + k0, 256, tid);
    stage_swz<128, 7, 2, 256>(bs, Bb + k0, 256, tid);
    __syncthreads();
#pragma unroll
    for (int ks = 0; ks < 2; ++ks) {
      int kb = ks * 64 + g * 16;
      bf16x8 a0 = ldfrag<128, 7>(as, wm * 32 + lr, kb);
      bf16x8 a1 = ldfrag<128, 7>(as, wm * 32 + 16 + lr, kb);
      bf16x8 b0 = ldfrag<128, 7>(bs, wn * 32 + lr, kb);
      bf16x8 b1 = ldfrag<128, 7>(bs, wn * 32 + 16 + lr, kb);
      acc[0][0] = mfma16(a0, b0, acc[0][0]);
      acc[0][1] = mfma16(a0, b1, acc[0][1]);
      acc[1][0] = mfma16(a1, b0, acc[1][0]);
      acc[1][1] = mfma16(a1, b1, acc[1][1]);
    }
    __syncthreads();
  }

  int mb = blockIdx.x * 64 + wm * 32;
  int nb = blockIdx.y * 64 + wn * 32;
#pragma unroll
  for (int mi = 0; mi < 2; ++mi)
#pragma unroll
    for (int ni = 0; ni < 2; ++ni)
#pragma unroll
      for (int e = 0; e < 4; ++e) {
        int m = mb + mi * 16 + 4 * g + e;
        int n = nb + ni * 16 + lr;
        long addr = (long)z * 1048576 + (long)m * 4096 + n;
        outp[addr] = acc[mi][ni][e] + bias[m] + resid[addr];
      }
}

// ---------------- flash attention: 4-wave blocks, c-split twins, dbuf ----------------
// 512 blocks (b = bid&7 XCD-aligned), 256 thr = 4 waves: rg = wave>>1 (32-row group),
// chalf = wave&1 (O c-half, QK^T duplicated across twins). Lane owns ONE q-row
// (swapped QK^T). KVBLK=32 DOUBLE-buffered: loop = {issue stage(t+1), compute(t),
// barrier} -- staging latency hides under MFMA+softmax. QK = 2 independent 8-chains.
__global__ __launch_bounds__(256, 2) void attn_flash(
    const u16* __restrict__ qt, const u16* __restrict__ kgp,
    const u16* __restrict__ vgp, u16* __restrict__ ot) {
  __shared__ __align__(16) u16 ksT[2][8192];   // [buf][cg 32][j 32][8] = 2x16KB
  __shared__ __align__(16) u16 vsT[2][8192];   // [buf][g 4][c 256][8] = 2x16KB
  __shared__ float fws[128];                   // [wave][32] broadcast scratch

  int tid = threadIdx.x;
  int lane = tid & 63;
  int h = lane >> 5, lr = lane & 31;
  int wave = tid >> 6;
  int rg = wave >> 1, chalf = wave & 1;
  int bid = blockIdx.x;
  long b = bid & 7;
  int i0 = (bid >> 3) * 64;

  const u16* kb = kgp + b * 1048576;
  const u16* vb = vgp + b * 1048576;
  float* fw = fws + wave * 32;

  // Q: lane owns q-row (i0 + rg*32 + lr); frag kk holds c = kk*16 + 8h + e
  const u16* qrow = qt + ((b * 4096 + i0 + rg * 32 + lr) << 8) + h * 8;
  bf16x8 qreg[16];
#pragma unroll
  for (int kk = 0; kk < 16; ++kk)
    qreg[kk] = *(const bf16x8*)(qrow + kk * 16);

  f32x16 zero16 = {0,0,0,0,0,0,0,0,0,0,0,0,0,0,0,0};
  f32x16 acc[4];                 // O[row pattern][c = chalf*128 + ct*32 + lr]
#pragma unroll
  for (int ct = 0; ct < 4; ++ct) acc[ct] = zero16;
  float mrun = -3e38f, lsum = 0.f;

  stage_lin<4, 256>(ksT[0], kb, tid);
  stage_lin<4, 256>(vsT[0], vb, tid);
  __syncthreads();

  for (int t = 0; t < 128; ++t) {
    int cur = t & 1;
    if (t < 127) {
      stage_lin<4, 256>(ksT[cur ^ 1], kb + (long)(t + 1) * 8192, tid);
      stage_lin<4, 256>(vsT[cur ^ 1], vb + (long)(t + 1) * 8192, tid);
    }
    const u16* ksl = ksT[cur];
    const u16* vsl = vsT[cur];

    // S^T = K * Q (log2 units): two independent 8-deep MFMA chains
    f32x16 sa0 = zero16, sa1 = zero16;
    __builtin_amdgcn_s_setprio(1);
#pragma unroll
    for (int kk = 0; kk < 8; ++kk) {
      bf16x8 kf0 = *(const bf16x8*)(ksl + ((2 * (2 * kk) + h) * 32 + lr) * 8);
      bf16x8 kf1 = *(const bf16x8*)(ksl + ((2 * (2 * kk + 1) + h) * 32 + lr) * 8);
      sa0 = mfma32(kf0, qreg[2 * kk], sa0);
      sa1 = mfma32(kf1, qreg[2 * kk + 1], sa1);
    }
    __builtin_amdgcn_s_setprio(0);
    f32x16 sacc = sa0 + sa1;

    // row max: 16 regs + xor-32 (partner lane holds the other 16 j's)
    float mloc = sacc[0];
#pragma unroll
    for (int r = 1; r < 16; ++r) mloc = fmaxf(mloc, sacc[r]);
    mloc = fmaxf(mloc, __shfl_xor(mloc, 32));

    // defer-max: rescale only when max grew by > 8 (log2 units)
    if (!__all(mloc - mrun <= 8.f)) {
      float mnew = fmaxf(mrun, mloc);
      float al = exp2f(mrun - mnew);
      mrun = mnew;
      lsum *= al;
      if (h == 0) fw[lr] = al;
      asm volatile("s_waitcnt lgkmcnt(0)" ::: "memory");
      f32x4 fq0 = *(const f32x4*)&fw[4 * h];
      f32x4 fq1 = *(const f32x4*)&fw[8 + 4 * h];
      f32x4 fq2 = *(const f32x4*)&fw[16 + 4 * h];
      f32x4 fq3 = *(const f32x4*)&fw[24 + 4 * h];
      f32x16 alv;
#pragma unroll
      for (int e = 0; e < 4; ++e) {
        alv[e] = fq0[e]; alv[4 + e] = fq1[e]; alv[8 + e] = fq2[e]; alv[12 + e] = fq3[e];
      }
#pragma unroll
      for (int ct = 0; ct < 4; ++ct) acc[ct] *= alv;
    }

    // P = exp2(S - m), pack bf16 pairs; per-lane partial lsum
    u32 u[8];
#pragma unroll
    for (int m = 0; m < 8; ++m) {
      float p0 = exp2f(sacc[2 * m] - mrun);
      float p1 = exp2f(sacc[2 * m + 1] - mrun);
      lsum += p0 + p1;
      u[m] = (u32)f2bf(p0) | ((u32)f2bf(p1) << 16);
    }
    // half-exchange with lane^32 to assemble PV A-fragments
    u32 rv[4];
#pragma unroll
    for (int kt2 = 0; kt2 < 2; ++kt2)
#pragma unroll
      for (int idx = 0; idx < 2; ++idx) {
        u32 send = h ? u[4 * kt2 + idx] : u[4 * kt2 + 2 + idx];
        rv[kt2 * 2 + idx] = (u32)__shfl_xor((int)send, 32);
      }
    union { u32 wd[4]; bf16x8 v; } pf[2];
#pragma unroll
    for (int kt2 = 0; kt2 < 2; ++kt2) {
      pf[kt2].wd[0] = h ? rv[kt2 * 2] : u[4 * kt2];
      pf[kt2].wd[1] = h ? rv[kt2 * 2 + 1] : u[4 * kt2 + 1];
      pf[kt2].wd[2] = h ? u[4 * kt2 + 2] : rv[kt2 * 2];
      pf[kt2].wd[3] = h ? u[4 * kt2 + 3] : rv[kt2 * 2 + 1];
    }

    // PV for this wave's c-half: O[i][c] += P[i][j] * V[c][j]
    __builtin_amdgcn_s_setprio(1);
#pragma unroll
    for (int ct = 0; ct < 4; ++ct) {
      int c = chalf * 128 + ct * 32 + lr;
      bf16x8 vf0 = *(const bf16x8*)(vsl + ((long)h * 256 + c) * 8);
      bf16x8 vf1 = *(const bf16x8*)(vsl + ((long)(2 + h) * 256 + c) * 8);
      acc[ct] = mfma32(pf[0].v, vf0, acc[ct]);
      acc[ct] = mfma32(pf[1].v, vf1, acc[ct]);
    }
    __builtin_amdgcn_s_setprio(0);

    __syncthreads();   // prefetch (t+1) complete; all reads of cur done
  }

  // epilogue: total lsum per row, broadcast 1/lsum, scale, store
  lsum += __shfl_xor(lsum, 32);
  if (h == 0) fw[lr] = 1.0f / lsum;
  asm volatile("s_waitcnt lgkmcnt(0)" ::: "memory");
  f32x4 fq0 = *(const f32x4*)&fw[4 * h];
  f32x4 fq1 = *(const f32x4*)&fw[8 + 4 * h];
  f32x4 fq2 = *(const f32x4*)&fw[16 + 4 * h];
  f32x4 fq3 = *(const f32x4*)&fw[24 + 4 * h];
  f32x16 rlv;
#pragma unroll
  for (int e = 0; e < 4; ++e) {
    rlv[e] = fq0[e]; rlv[4 + e] = fq1[e]; rlv[8 + e] = fq2[e]; rlv[12 + e] = fq3[e];
  }
  u16* ob = ot + ((b * 4096 + i0 + rg * 32) << 8) + chalf * 128;
#pragma unroll
  for (int ct = 0; ct < 4; ++ct) {
    int cl = ct * 32 + lr;
#pragma unroll
    for (int q = 0; q < 4; ++q)
#pragma unroll
      for (int e = 0; e < 4; ++e) {
        int i = 8 * q + 4 * h + e;
        ob[(long)i * 256 + cl] = f2bf(acc[ct][4 * q + e] * rlv[4 * q + e]);
      }
  }
}

// ---------------- launcher ----------------
extern "C" void kernel_launch(void* const* d_in, const int* in_sizes, int n_in,
                              void* d_out, int out_size, void* d_ws, size_t ws_size,
                              hipStream_t stream) {
  const float* x     = (const float*)d_in[0];
  const float* gamma = (const float*)d_in[1];
  const float* beta  = (const float*)d_in[2];
  const float* wq = (const float*)d_in[3];
  const float* bq = (const float*)d_in[4];
  const float* wk = (const float*)d_in[5];
  const float* bk = (const float*)d_in[6];
  const float* wv = (const float*)d_in[7];
  const float* bv = (const float*)d_in[8];
  const float* wp = (const float*)d_in[9];
  const float* bp = (const float*)d_in[10];

  char* ws = (char*)d_ws;
  const long SZ = 16777216;            // one [B][N][C] bf16 tensor
  u16* ht  = (u16*)(ws);
  u16* qtb = (u16*)(ws + SZ);
  u16* ktb = (u16*)(ws + 2 * SZ);      // granule-planar K
  u16* vcb = (u16*)(ws + 3 * SZ);      // granule-planar V
  u16* wbf = (u16*)(ws + 4 * SZ);      // wq|wk|wv|wp, 65536 u16 each
  u16* otb = ht;                       // h dead after QKV; reuse for attn output

  convert_w<<<1024, 256, 0, stream>>>(wq, wk, wv, wp, wbf);
  gn_kernel<<<128, 256, 0, stream>>>(x, gamma, beta, ht);

  dim3 gq(512, 4, 1);   // M=B*N=32768 rows, Nn=256
  gemm_qkv<<<gq, 256, 0, stream>>>(ht, wbf, qtb, ktb, vcb, bq, bk, bv);

  attn_flash<<<512, 256, 0, stream>>>(qtb, ktb, vcb, otb);

  dim3 gp(4, 64, 8);
  gemm_proj<<<gp, 256, 0, stream>>>(wbf + 3 * 65536, otb, (float*)d_out, bp, x);
}

// Round 9
// 346.729 us; speedup vs baseline: 1.2413x; 1.2413x over previous
//
#include <hip/hip_runtime.h>
#include <hip/hip_bf16.h>

// AttnBlock2d: GN -> q/k/v 1x1conv -> softmax(q^T k / sqrt(C)) -> v@alpha -> proj -> +x
// B=8, C=256, H*W=4096. bf16 MFMA, fp32 accum.
// R9 = R8 with two fixes:
//  (1) attn_merge rewritten without the &uint4 OOB-read UB (proper 16-elem locals,
//      static indexing only) -- R8's 0.455 absmax came from reading past a uint4.
//  (2) ml0/ml1 scratch moved into d_out's unused upper half (keeps ws footprint at
//      the proven 64.5MB; d_out = 32MB, partials+ml = 16.5MB, written before read).
// Structure unchanged: block-level j-split (no c-twin duplication), 1024 blocks x
// 2 waves, full-c waves, 33KB LDS -> 4 independent blocks/CU for stall overlap.

typedef unsigned int u32;
typedef unsigned short u16;
typedef __bf16 bf16x8 __attribute__((ext_vector_type(8)));
typedef float f32x4 __attribute__((ext_vector_type(4)));
typedef float f32x16 __attribute__((ext_vector_type(16)));

#define GAS __attribute__((address_space(1)))
#define LAS __attribute__((address_space(3)))

__device__ __forceinline__ u16 f2bf(float f) {
  union { float f; u32 u; } v; v.f = f;
  return (u16)((v.u + 0x7fffu + ((v.u >> 16) & 1u)) >> 16);
}

__device__ __forceinline__ f32x4 mfma16(bf16x8 a, bf16x8 b, f32x4 c) {
  return __builtin_amdgcn_mfma_f32_16x16x32_bf16(a, b, c, 0, 0, 0);
}
__device__ __forceinline__ f32x16 mfma32(bf16x8 a, bf16x8 b, f32x16 c) {
  return __builtin_amdgcn_mfma_f32_32x32x16_bf16(a, b, c, 0, 0, 0);
}

// Stage [ROWS][ROWB bytes] row-major bf16 tile into LDS via global_load_lds,
// XOR swizzle on the SOURCE side (linear dest + inverse-swz source). (GEMMs only.)
template<int ROWB, int MASK, int ITERS, int NT>
__device__ __forceinline__ void stage_swz(u16* lds, const u16* g, int ldg, int tid) {
#pragma unroll
  for (int it = 0; it < ITERS; ++it) {
    int idx = it * NT + tid;
    int off = idx * 16;
    int row = off / ROWB;
    int slot = off % ROWB;
    int sem = slot ^ ((row & MASK) << 4);
    const u16* src = g + (long)row * ldg + (sem >> 1);
    u16* dst = lds + (long)(idx & ~63) * 8;
    __builtin_amdgcn_global_load_lds((const GAS u32*)src, (LAS u32*)dst, 16, 0, 0);
  }
}

// Stage a fully-contiguous region: linear global -> linear LDS, coalesced.
template<int ITERS, int NT>
__device__ __forceinline__ void stage_lin(u16* lds, const u16* g, int tid) {
#pragma unroll
  for (int it = 0; it < ITERS; ++it) {
    int idx = it * NT + tid;
    const u16* src = g + (long)idx * 8;
    u16* dst = lds + (long)(idx & ~63) * 8;
    __builtin_amdgcn_global_load_lds((const GAS u32*)src, (LAS u32*)dst, 16, 0, 0);
  }
}

template<int ROWB, int MASK>
__device__ __forceinline__ bf16x8 ldfrag(const u16* lds, int row, int kbyte) {
  int off = row * ROWB + (kbyte ^ ((row & MASK) << 4));
  return *(const bf16x8*)((const char*)lds + off);
}

// ---------------- weight fp32 -> bf16 ----------------
__global__ __launch_bounds__(256) void convert_w(
    const float* __restrict__ w0, const float* __restrict__ w1,
    const float* __restrict__ w2, const float* __restrict__ w3,
    u16* __restrict__ out) {
  int i = blockIdx.x * 256 + threadIdx.x;
  int seg = i >> 16, idx = i & 65535;
  const float* w = seg == 0 ? w0 : seg == 1 ? w1 : seg == 2 ? w2 : w3;
  out[i] = f2bf(w[idx]);
}

// ---------------- GroupNorm: x [B][C][N] fp32 -> h_t [B][N][C] bf16 ----------------
__global__ __launch_bounds__(256) void gn_kernel(
    const float* __restrict__ x, const float* __restrict__ gamma,
    const float* __restrict__ beta, u16* __restrict__ ht) {
  int tid = threadIdx.x;
  int b = blockIdx.x >> 4;
  int grp = blockIdx.x & 15;
  const float* xg = x + ((long)b * 256 + grp * 16) * 4096;

  float s = 0.f, ss = 0.f;
  const float4* x4 = (const float4*)xg;
#pragma unroll 4
  for (int it = 0; it < 64; ++it) {
    float4 v = x4[it * 256 + tid];
    s += v.x + v.y + v.z + v.w;
    ss += v.x * v.x + v.y * v.y + v.z * v.z + v.w * v.w;
  }
#pragma unroll
  for (int d = 1; d < 64; d <<= 1) {
    s += __shfl_xor(s, d);
    ss += __shfl_xor(ss, d);
  }
  __shared__ float red[10];
  int lane = tid & 63, wave = tid >> 6;
  if (lane == 0) { red[wave] = s; red[4 + wave] = ss; }
  __syncthreads();
  if (tid == 0) {
    float S = red[0] + red[1] + red[2] + red[3];
    float SS = red[4] + red[5] + red[6] + red[7];
    float mean = S * (1.f / 65536.f);
    float var = SS * (1.f / 65536.f) - mean * mean;
    red[8] = mean;
    red[9] = rsqrtf(var + 1e-6f);
  }
  __syncthreads();
  float mean = red[8], rstd = red[9];

  float a[16], bb[16];
#pragma unroll
  for (int c = 0; c < 16; ++c) {
    float gm = gamma[grp * 16 + c];
    float bt = beta[grp * 16 + c];
    a[c] = gm * rstd;
    bb[c] = bt - mean * a[c];
  }
  u16* hb = ht + (long)b * 4096 * 256 + grp * 16;
  for (int it = 0; it < 16; ++it) {
    int n = it * 256 + tid;
    __align__(16) u16 tmp[16];
#pragma unroll
    for (int c = 0; c < 16; ++c)
      tmp[c] = f2bf(xg[(long)c * 4096 + n] * a[c] + bb[c]);
    u16* dst = hb + (long)n * 256;
    ((uint4*)dst)[0] = ((uint4*)tmp)[0];
    ((uint4*)dst)[1] = ((uint4*)tmp)[1];
  }
}

// ---------------- fused QKV GEMM ----------------
// q_t out [pos][o] bf16 (pre-scaled by C^-0.5*log2e).
// k out granule-planar: kgp[b][jt=pos/32][cg=o/8][j=pos&31][o&7].
// v out granule-planar: vgp[b][jt=pos/32][g=(pos/8)&3][o][pos&7].
__global__ __launch_bounds__(256) void gemm_qkv(
    const u16* __restrict__ ht, const u16* __restrict__ wbf,
    u16* __restrict__ qtb, u16* __restrict__ ktb, u16* __restrict__ vcb,
    const float* __restrict__ bq, const float* __restrict__ bk,
    const float* __restrict__ bv) {
  __shared__ __align__(16) u16 as[64 * 64];
  __shared__ __align__(16) u16 bqs[64 * 64];
  __shared__ __align__(16) u16 bks[64 * 64];
  __shared__ __align__(16) u16 bvs[64 * 64];
  int tid = threadIdx.x;
  int lane = tid & 63, wave = tid >> 6;
  int g = lane >> 4, lr = lane & 15;
  int wm = wave >> 1, wn = wave & 1;
  const u16* Ab = ht + (long)blockIdx.x * 64 * 256;
  const u16* Wq = wbf + (long)blockIdx.y * 64 * 256;

  f32x4 zero = {0.f, 0.f, 0.f, 0.f};
  f32x4 acc[3][2][2];
#pragma unroll
  for (int w = 0; w < 3; ++w)
#pragma unroll
    for (int i = 0; i < 2; ++i)
#pragma unroll
      for (int j = 0; j < 2; ++j) acc[w][i][j] = zero;

  for (int k0 = 0; k0 < 256; k0 += 64) {
    stage_swz<128, 7, 2, 256>(as, Ab + k0, 256, tid);
    stage_swz<128, 7, 2, 256>(bqs, Wq + k0, 256, tid);
    stage_swz<128, 7, 2, 256>(bks, Wq + 65536 + k0, 256, tid);
    stage_swz<128, 7, 2, 256>(bvs, Wq + 131072 + k0, 256, tid);
    __syncthreads();
#pragma unroll
    for (int ks = 0; ks < 2; ++ks) {
      int kb = ks * 64 + g * 16;
      bf16x8 a0 = ldfrag<128, 7>(as, wm * 32 + lr, kb);
      bf16x8 a1 = ldfrag<128, 7>(as, wm * 32 + 16 + lr, kb);
      __builtin_amdgcn_s_setprio(1);
      {
        bf16x8 b0 = ldfrag<128, 7>(bqs, wn * 32 + lr, kb);
        bf16x8 b1 = ldfrag<128, 7>(bqs, wn * 32 + 16 + lr, kb);
        acc[0][0][0] = mfma16(a0, b0, acc[0][0][0]);
        acc[0][0][1] = mfma16(a0, b1, acc[0][0][1]);
        acc[0][1][0] = mfma16(a1, b0, acc[0][1][0]);
        acc[0][1][1] = mfma16(a1, b1, acc[0][1][1]);
      }
      {
        bf16x8 b0 = ldfrag<128, 7>(bks, wn * 32 + lr, kb);
        bf16x8 b1 = ldfrag<128, 7>(bks, wn * 32 + 16 + lr, kb);
        acc[1][0][0] = mfma16(a0, b0, acc[1][0][0]);
        acc[1][0][1] = mfma16(a0, b1, acc[1][0][1]);
        acc[1][1][0] = mfma16(a1, b0, acc[1][1][0]);
        acc[1][1][1] = mfma16(a1, b1, acc[1][1][1]);
      }
      {
        bf16x8 b0 = ldfrag<128, 7>(bvs, wn * 32 + lr, kb);
        bf16x8 b1 = ldfrag<128, 7>(bvs, wn * 32 + 16 + lr, kb);
        acc[2][0][0] = mfma16(a0, b0, acc[2][0][0]);
        acc[2][0][1] = mfma16(a0, b1, acc[2][0][1]);
        acc[2][1][0] = mfma16(a1, b0, acc[2][1][0]);
        acc[2][1][1] = mfma16(a1, b1, acc[2][1][1]);
      }
      __builtin_amdgcn_s_setprio(0);
    }
    __syncthreads();
  }

  const float QSC = 0.0625f * 1.44269504f;   // C^-0.5 * log2(e), folded into q
  int mb = blockIdx.x * 64 + wm * 32;
  int nb = blockIdx.y * 64 + wn * 32;
  int b_ = mb >> 12;
  int posb = mb & 4095;
#pragma unroll
  for (int mi = 0; mi < 2; ++mi)
#pragma unroll
    for (int ni = 0; ni < 2; ++ni) {
      int n = nb + ni * 16 + lr;
      int pos0 = posb + mi * 16 + 4 * g;          // rows pos0..pos0+3 (same 32-tile)
      int jt = pos0 >> 5, jj = pos0 & 31;
      long kbase = (long)b_ * 1048576 + (long)jt * 8192 + (n >> 3) * 256 + jj * 8 + (n & 7);
      __align__(8) u16 v4[4];
#pragma unroll
      for (int e = 0; e < 4; ++e) {
        int m = mb + mi * 16 + 4 * g + e;
        long addr = (long)m * 256 + n;
        qtb[addr] = f2bf((acc[0][mi][ni][e] + bq[n]) * QSC);
        ktb[kbase + e * 8] = f2bf(acc[1][mi][ni][e] + bk[n]);
        v4[e] = f2bf(acc[2][mi][ni][e] + bv[n]);
      }
      int gg = (pos0 >> 3) & 3, js = pos0 & 7;
      *(uint2*)(vcb + (long)b_ * 1048576 + (long)jt * 8192 + gg * 2048 + n * 8 + js)
          = *(uint2*)v4;
    }
}

// ---------------- proj GEMM + residual: D[m=o][n=pos] fp32 ----------------
__global__ __launch_bounds__(256) void gemm_proj(
    const u16* __restrict__ A, const u16* __restrict__ Bt,
    float* __restrict__ outp, const float* __restrict__ bias,
    const float* __restrict__ resid) {
  __shared__ __align__(16) u16 as[64 * 64];
  __shared__ __align__(16) u16 bs[64 * 64];
  int tid = threadIdx.x;
  int lane = tid & 63, wave = tid >> 6;
  int g = lane >> 4, lr = lane & 15;
  int wm = wave >> 1, wn = wave & 1;
  int z = blockIdx.z;
  const u16* Ab = A + (long)blockIdx.x * 64 * 256;
  const u16* Bb = Bt + (long)z * 4096 * 256 + (long)blockIdx.y * 64 * 256;

  f32x4 zero = {0.f, 0.f, 0.f, 0.f};
  f32x4 acc[2][2];
#pragma unroll
  for (int i = 0; i < 2; ++i)
#pragma unroll
    for (int j = 0; j < 2; ++j) acc[i][j] = zero;

  for (int k0 = 0; k0 < 256; k0 += 64) {
    stage_swz<128, 7, 2, 256>(as, Ab + k0, 256, tid);
    stage_swz<128, 7, 2, 256>(bs, Bb + k0, 256, tid);
    __syncthreads();
#pragma unroll
    for (int ks = 0; ks < 2; ++ks) {
      int kb = ks * 64 + g * 16;
      bf16x8 a0 = ldfrag<128, 7>(as, wm * 32 + lr, kb);
      bf16x8 a1 = ldfrag<128, 7>(as, wm * 32 + 16 + lr, kb);
      bf16x8 b0 = ldfrag<128, 7>(bs, wn * 32 + lr, kb);
      bf16x8 b1 = ldfrag<128, 7>(bs, wn * 32 + 16 + lr, kb);
      acc[0][0] = mfma16(a0, b0, acc[0][0]);
      acc[0][1] = mfma16(a0, b1, acc[0][1]);
      acc[1][0] = mfma16(a1, b0, acc[1][0]);
      acc[1][1] = mfma16(a1, b1, acc[1][1]);
    }
    __syncthreads();
  }

  int mb = blockIdx.x * 64 + wm * 32;
  int nb = blockIdx.y * 64 + wn * 32;
#pragma unroll
  for (int mi = 0; mi < 2; ++mi)
#pragma unroll
    for (int ni = 0; ni < 2; ++ni)
#pragma unroll
      for (int e = 0; e < 4; ++e) {
        int m = mb + mi * 16 + 4 * g + e;
        int n = nb + ni * 16 + lr;
        long addr = (long)z * 1048576 + (long)m * 4096 + n;
        outp[addr] = acc[mi][ni][e] + bias[m] + resid[addr];
      }
}

// ---------------- flash attention: block-level j-split, full-c waves ----------------
// 1024 blocks: b = bid&7 (XCD-aligned), jhalf = (bid>>3)&1, itile = bid>>4.
// 128 thr = 2 waves (rg), 32 q-rows each, lane owns one q-row (swapped QK^T).
// Full c (acc 8 x f32x16 = 128 AGPR), single softmax copy. KVBLK=32 single-buffered
// (33KB LDS -> 4 independent blocks/CU; 2048 waves = 2/SIMD; cross-block overlap).
// Outputs: UNNORMALIZED bf16 partial O + per-row (m, lsum); merged by attn_merge.
__global__ __launch_bounds__(128, 2) void attn_flash(
    const u16* __restrict__ qt, const u16* __restrict__ kgp,
    const u16* __restrict__ vgp, u16* __restrict__ part0, u16* __restrict__ part1,
    float2* __restrict__ ml0, float2* __restrict__ ml1) {
  __shared__ __align__(16) u16 ksT[8192];   // [cg 32][j 32][8] = 16KB
  __shared__ __align__(16) u16 vsT[8192];   // [g 4][c 256][8] = 16KB
  __shared__ float fws[64];                 // [wave][32] broadcast scratch

  int tid = threadIdx.x;
  int lane = tid & 63;
  int h = lane >> 5, lr = lane & 31;
  int rg = tid >> 6;
  int bid = blockIdx.x;
  long b = bid & 7;
  int jhalf = (bid >> 3) & 1;
  int i0 = (bid >> 4) * 64;

  const u16* kb = kgp + b * 1048576 + (long)(jhalf * 64) * 8192;
  const u16* vb = vgp + b * 1048576 + (long)(jhalf * 64) * 8192;
  float* fw = fws + rg * 32;

  // Q: lane owns q-row (i0 + rg*32 + lr); frag kk holds c = kk*16 + 8h + e
  const u16* qrow = qt + ((b * 4096 + i0 + rg * 32 + lr) << 8) + h * 8;
  bf16x8 qreg[16];
#pragma unroll
  for (int kk = 0; kk < 16; ++kk)
    qreg[kk] = *(const bf16x8*)(qrow + kk * 16);

  f32x16 zero16 = {0,0,0,0,0,0,0,0,0,0,0,0,0,0,0,0};
  f32x16 acc[8];                 // O[row pattern][c = ct*32 + lr]
#pragma unroll
  for (int ct = 0; ct < 8; ++ct) acc[ct] = zero16;
  float mrun = -3e38f, lsum = 0.f;

  for (int t = 0; t < 64; ++t) {
    __syncthreads();                                   // prev compute done
    stage_lin<8, 128>(ksT, kb + (long)t * 8192, tid);
    stage_lin<8, 128>(vsT, vb + (long)t * 8192, tid);
    __syncthreads();                                   // stage complete

    // S^T = K * Q (log2 units): D col = lane&31 = own q-row, D row = j
    f32x16 sacc = zero16;
    __builtin_amdgcn_s_setprio(1);
#pragma unroll
    for (int kk = 0; kk < 16; ++kk) {
      bf16x8 kf = *(const bf16x8*)(ksT + ((2 * kk + h) * 32 + lr) * 8);
      sacc = mfma32(kf, qreg[kk], sacc);
    }
    __builtin_amdgcn_s_setprio(0);

    // row max: pairwise tree over 16 regs + xor-32 (partner has other 16 j's)
    float m0 = fmaxf(fmaxf(sacc[0], sacc[1]), fmaxf(sacc[2], sacc[3]));
    float m1 = fmaxf(fmaxf(sacc[4], sacc[5]), fmaxf(sacc[6], sacc[7]));
    float m2 = fmaxf(fmaxf(sacc[8], sacc[9]), fmaxf(sacc[10], sacc[11]));
    float m3 = fmaxf(fmaxf(sacc[12], sacc[13]), fmaxf(sacc[14], sacc[15]));
    float mloc = fmaxf(fmaxf(m0, m1), fmaxf(m2, m3));
    mloc = fmaxf(mloc, __shfl_xor(mloc, 32));

    // defer-max: rescale only when max grew by > 8 (log2 units)
    if (!__all(mloc - mrun <= 8.f)) {
      float mnew = fmaxf(mrun, mloc);
      float al = exp2f(mrun - mnew);
      mrun = mnew;
      lsum *= al;
      if (h == 0) fw[lr] = al;
      asm volatile("s_waitcnt lgkmcnt(0)" ::: "memory");
      f32x4 fq0 = *(const f32x4*)&fw[4 * h];
      f32x4 fq1 = *(const f32x4*)&fw[8 + 4 * h];
      f32x4 fq2 = *(const f32x4*)&fw[16 + 4 * h];
      f32x4 fq3 = *(const f32x4*)&fw[24 + 4 * h];
      f32x16 alv;
#pragma unroll
      for (int e = 0; e < 4; ++e) {
        alv[e] = fq0[e]; alv[4 + e] = fq1[e]; alv[8 + e] = fq2[e]; alv[12 + e] = fq3[e];
      }
#pragma unroll
      for (int ct = 0; ct < 8; ++ct) acc[ct] *= alv;
    }

    // P = exp2(S - m); pack bf16 pairs via v_cvt_pk_bf16_f32 (1 instr / pair)
    u32 u[8];
#pragma unroll
    for (int m = 0; m < 8; ++m) {
      float p0 = exp2f(sacc[2 * m] - mrun);
      float p1 = exp2f(sacc[2 * m + 1] - mrun);
      lsum += p0 + p1;
      asm volatile("v_cvt_pk_bf16_f32 %0, %1, %2" : "=v"(u[m]) : "v"(p0), "v"(p1));
    }
    // half-exchange with lane^32 to assemble PV A-fragments
    u32 rv[4];
#pragma unroll
    for (int kt2 = 0; kt2 < 2; ++kt2)
#pragma unroll
      for (int idx = 0; idx < 2; ++idx) {
        u32 send = h ? u[4 * kt2 + idx] : u[4 * kt2 + 2 + idx];
        rv[kt2 * 2 + idx] = (u32)__shfl_xor((int)send, 32);
      }
    union { u32 wd[4]; bf16x8 v; } pf[2];
#pragma unroll
    for (int kt2 = 0; kt2 < 2; ++kt2) {
      pf[kt2].wd[0] = h ? rv[kt2 * 2] : u[4 * kt2];
      pf[kt2].wd[1] = h ? rv[kt2 * 2 + 1] : u[4 * kt2 + 1];
      pf[kt2].wd[2] = h ? u[4 * kt2 + 2] : rv[kt2 * 2];
      pf[kt2].wd[3] = h ? u[4 * kt2 + 3] : rv[kt2 * 2 + 1];
    }

    // PV full-c: O[i][c] += P[i][j] * V[c][j]
    __builtin_amdgcn_s_setprio(1);
#pragma unroll
    for (int ct = 0; ct < 8; ++ct) {
      int c = ct * 32 + lr;
      bf16x8 vf0 = *(const bf16x8*)(vsT + ((long)h * 256 + c) * 8);
      bf16x8 vf1 = *(const bf16x8*)(vsT + ((long)(2 + h) * 256 + c) * 8);
      acc[ct] = mfma32(pf[0].v, vf0, acc[ct]);
      acc[ct] = mfma32(pf[1].v, vf1, acc[ct]);
    }
    __builtin_amdgcn_s_setprio(0);
  }

  // epilogue: store UNNORMALIZED partial O (bf16) + per-row (m, lsum)
  lsum += __shfl_xor(lsum, 32);
  u16* pout = jhalf ? part1 : part0;
  float2* mlo = jhalf ? ml1 : ml0;
  if (h == 0)
    mlo[b * 4096 + i0 + rg * 32 + lr] = make_float2(mrun, lsum);
  u16* ob = pout + ((b * 4096 + i0 + rg * 32) << 8);
#pragma unroll
  for (int ct = 0; ct < 8; ++ct) {
    int c = ct * 32 + lr;
#pragma unroll
    for (int q = 0; q < 4; ++q)
#pragma unroll
      for (int e = 0; e < 4; ++e) {
        int i = 8 * q + 4 * h + e;
        ob[(long)i * 256 + c] = f2bf(acc[ct][4 * q + e]);
      }
  }
}

// ---------------- merge the two j-half partials ----------------
// out[row][c] = (w0*O0 + w1*O1) / (w0*l0 + w1*l1), w_h = exp2(m_h - max(m0,m1)).
// 2048 blocks x 256 thr: 16 rows/block, 16 c per thread (2x bf16x8, static idx only).
__global__ __launch_bounds__(256) void attn_merge(
    const u16* __restrict__ p0, const u16* __restrict__ p1,
    const float2* __restrict__ ml0, const float2* __restrict__ ml1,
    u16* __restrict__ out) {
  int tid = threadIdx.x;
  int row = blockIdx.x * 16 + (tid >> 4);
  int cs = (tid & 15) * 16;
  float2 a = ml0[row], c = ml1[row];
  float M = fmaxf(a.x, c.x);
  float w0 = exp2f(a.x - M), w1 = exp2f(c.x - M);
  float rl = 1.0f / (w0 * a.y + w1 * c.y);
  float f0 = w0 * rl, f1 = w1 * rl;

  long base = (long)row * 256 + cs;
  bf16x8 a0 = *(const bf16x8*)(p0 + base);
  bf16x8 a1 = *(const bf16x8*)(p0 + base + 8);
  bf16x8 c0 = *(const bf16x8*)(p1 + base);
  bf16x8 c1 = *(const bf16x8*)(p1 + base + 8);
  __align__(16) u16 o[16];
#pragma unroll
  for (int k = 0; k < 8; ++k) {
    o[k]     = f2bf(f0 * (float)a0[k] + f1 * (float)c0[k]);
    o[k + 8] = f2bf(f0 * (float)a1[k] + f1 * (float)c1[k]);
  }
  *(uint4*)(out + base) = ((uint4*)o)[0];
  *(uint4*)(out + base + 8) = ((uint4*)o)[1];
}

// ---------------- launcher ----------------
extern "C" void kernel_launch(void* const* d_in, const int* in_sizes, int n_in,
                              void* d_out, int out_size, void* d_ws, size_t ws_size,
                              hipStream_t stream) {
  const float* x     = (const float*)d_in[0];
  const float* gamma = (const float*)d_in[1];
  const float* beta  = (const float*)d_in[2];
  const float* wq = (const float*)d_in[3];
  const float* bq = (const float*)d_in[4];
  const float* wk = (const float*)d_in[5];
  const float* bk = (const float*)d_in[6];
  const float* wv = (const float*)d_in[7];
  const float* bv = (const float*)d_in[8];
  const float* wp = (const float*)d_in[9];
  const float* bp = (const float*)d_in[10];

  char* ws = (char*)d_ws;
  const long SZ = 16777216;            // one [B][N][C] bf16 tensor
  u16* ht  = (u16*)(ws);
  u16* qtb = (u16*)(ws + SZ);
  u16* ktb = (u16*)(ws + 2 * SZ);      // granule-planar K
  u16* vcb = (u16*)(ws + 3 * SZ);      // granule-planar V
  u16* wbf = (u16*)(ws + 4 * SZ);      // wq|wk|wv|wp, 65536 u16 each (512KB)
  u16* part0 = ht;                     // h dead after QKV
  // d_out (32MB) doubles as scratch: partial1 (16MB) + ml0/ml1 (512KB).
  // All written before read; proj fully overwrites d_out at the end.
  u16* part1 = (u16*)d_out;
  float2* ml0 = (float2*)((char*)d_out + SZ);
  float2* ml1 = (float2*)((char*)d_out + SZ + 262144);

  convert_w<<<1024, 256, 0, stream>>>(wq, wk, wv, wp, wbf);
  gn_kernel<<<128, 256, 0, stream>>>(x, gamma, beta, ht);

  dim3 gq(512, 4, 1);   // M=B*N=32768 rows, Nn=256
  gemm_qkv<<<gq, 256, 0, stream>>>(ht, wbf, qtb, ktb, vcb, bq, bk, bv);

  attn_flash<<<1024, 128, 0, stream>>>(qtb, ktb, vcb, part0, part1, ml0, ml1);

  // merged attn output -> qtb (q dead after attn); proj reads it
  attn_merge<<<2048, 256, 0, stream>>>(part0, part1, ml0, ml1, qtb);

  dim3 gp(4, 64, 8);
  gemm_proj<<<gp, 256, 0, stream>>>(wbf + 3 * 65536, qtb, (float*)d_out, bp, x);
}

// Round 10
// 333.815 us; speedup vs baseline: 1.2893x; 1.0387x over previous
//
#include <hip/hip_runtime.h>
#include <hip/hip_bf16.h>

// AttnBlock2d: GN -> q/k/v 1x1conv -> softmax(q^T k / sqrt(C)) -> v@alpha -> proj -> +x
// B=8, C=256, H*W=4096. bf16 MFMA, fp32 accum.
// R10: attn/gn/merge unchanged (R9, verified). Both GEMMs rewritten on the attn-
// verified 32x32-MFMA + granule-planar-LDS pattern: [kh][row][8] tiles, linear
// conflict-free frag reads, per-lane global src staging, BK=32 single-buffered.
// gemm_qkv: 128pos x 128out x {q,k,v} per block (512 blocks, 4 waves, 192 AGPR).
// gemm_proj: 256o x 64pos per block (512 blocks, ~110 regs -> 3-4 waves/SIMD).

typedef unsigned int u32;
typedef unsigned short u16;
typedef __bf16 bf16x8 __attribute__((ext_vector_type(8)));
typedef float f32x4 __attribute__((ext_vector_type(4)));
typedef float f32x16 __attribute__((ext_vector_type(16)));

#define GAS __attribute__((address_space(1)))
#define LAS __attribute__((address_space(3)))

__device__ __forceinline__ u16 f2bf(float f) {
  union { float f; u32 u; } v; v.f = f;
  return (u16)((v.u + 0x7fffu + ((v.u >> 16) & 1u)) >> 16);
}

__device__ __forceinline__ f32x16 mfma32(bf16x8 a, bf16x8 b, f32x16 c) {
  return __builtin_amdgcn_mfma_f32_32x32x16_bf16(a, b, c, 0, 0, 0);
}

// Stage a fully-contiguous region: linear global -> linear LDS, coalesced.
template<int ITERS, int NT>
__device__ __forceinline__ void stage_lin(u16* lds, const u16* g, int tid) {
#pragma unroll
  for (int it = 0; it < ITERS; ++it) {
    int idx = it * NT + tid;
    const u16* src = g + (long)idx * 8;
    u16* dst = lds + (long)(idx & ~63) * 8;
    __builtin_amdgcn_global_load_lds((const GAS u32*)src, (LAS u32*)dst, 16, 0, 0);
  }
}

// Stage a [ROWS][256] row-major bf16 matrix slice (cols k0..k0+32) into
// granule-planar LDS [kh=4][ROWS][8]: per-lane global src, linear LDS dst.
template<int ROWS, int NT>
__device__ __forceinline__ void stage_gran(u16* lds, const u16* g, int k0, int tid) {
  constexpr int ITERS = 4 * ROWS / NT;
#pragma unroll
  for (int it = 0; it < ITERS; ++it) {
    int gi = it * NT + tid;
    int row = gi & (ROWS - 1);
    int kh = gi / ROWS;
    const u16* src = g + (long)row * 256 + k0 + kh * 8;
    u16* dst = lds + (long)(gi & ~63) * 8;
    __builtin_amdgcn_global_load_lds((const GAS u32*)src, (LAS u32*)dst, 16, 0, 0);
  }
}

// ---------------- weight fp32 -> bf16 ----------------
__global__ __launch_bounds__(256) void convert_w(
    const float* __restrict__ w0, const float* __restrict__ w1,
    const float* __restrict__ w2, const float* __restrict__ w3,
    u16* __restrict__ out) {
  int i = blockIdx.x * 256 + threadIdx.x;
  int seg = i >> 16, idx = i & 65535;
  const float* w = seg == 0 ? w0 : seg == 1 ? w1 : seg == 2 ? w2 : w3;
  out[i] = f2bf(w[idx]);
}

// ---------------- GroupNorm: x [B][C][N] fp32 -> h_t [B][N][C] bf16 ----------------
__global__ __launch_bounds__(256) void gn_kernel(
    const float* __restrict__ x, const float* __restrict__ gamma,
    const float* __restrict__ beta, u16* __restrict__ ht) {
  int tid = threadIdx.x;
  int b = blockIdx.x >> 4;
  int grp = blockIdx.x & 15;
  const float* xg = x + ((long)b * 256 + grp * 16) * 4096;

  float s = 0.f, ss = 0.f;
  const float4* x4 = (const float4*)xg;
#pragma unroll 4
  for (int it = 0; it < 64; ++it) {
    float4 v = x4[it * 256 + tid];
    s += v.x + v.y + v.z + v.w;
    ss += v.x * v.x + v.y * v.y + v.z * v.z + v.w * v.w;
  }
#pragma unroll
  for (int d = 1; d < 64; d <<= 1) {
    s += __shfl_xor(s, d);
    ss += __shfl_xor(ss, d);
  }
  __shared__ float red[10];
  int lane = tid & 63, wave = tid >> 6;
  if (lane == 0) { red[wave] = s; red[4 + wave] = ss; }
  __syncthreads();
  if (tid == 0) {
    float S = red[0] + red[1] + red[2] + red[3];
    float SS = red[4] + red[5] + red[6] + red[7];
    float mean = S * (1.f / 65536.f);
    float var = SS * (1.f / 65536.f) - mean * mean;
    red[8] = mean;
    red[9] = rsqrtf(var + 1e-6f);
  }
  __syncthreads();
  float mean = red[8], rstd = red[9];

  float a[16], bb[16];
#pragma unroll
  for (int c = 0; c < 16; ++c) {
    float gm = gamma[grp * 16 + c];
    float bt = beta[grp * 16 + c];
    a[c] = gm * rstd;
    bb[c] = bt - mean * a[c];
  }
  u16* hb = ht + (long)b * 4096 * 256 + grp * 16;
  for (int it = 0; it < 16; ++it) {
    int n = it * 256 + tid;
    __align__(16) u16 tmp[16];
#pragma unroll
    for (int c = 0; c < 16; ++c)
      tmp[c] = f2bf(xg[(long)c * 4096 + n] * a[c] + bb[c]);
    u16* dst = hb + (long)n * 256;
    ((uint4*)dst)[0] = ((uint4*)tmp)[0];
    ((uint4*)dst)[1] = ((uint4*)tmp)[1];
  }
}

// ---------------- fused QKV GEMM (32x32 MFMA, granule-planar LDS) ----------------
// Block: 128 pos x 128 out x {q,k,v}. 4 waves: wp = wave>>1 (pos sub 64),
// wo = wave&1 (out sub 64). D rows = pos (A=h frag), cols = o (B=w frag).
// q_t out [pos][o] bf16 (pre-scaled); k,v granule-planar (layouts as before).
__global__ __launch_bounds__(256, 2) void gemm_qkv(
    const u16* __restrict__ ht, const u16* __restrict__ wbf,
    u16* __restrict__ qtb, u16* __restrict__ ktb, u16* __restrict__ vcb,
    const float* __restrict__ bq, const float* __restrict__ bk,
    const float* __restrict__ bv) {
  __shared__ __align__(16) u16 as2[4 * 128 * 8];      // A [kh][pos][8], 8KB
  __shared__ __align__(16) u16 bs2[3][4 * 128 * 8];   // B per matrix, 24KB

  int tid = threadIdx.x;
  int lane = tid & 63;
  int h = lane >> 5, lr = lane & 31;
  int wave = tid >> 6;
  int wp = wave >> 1, wo = wave & 1;
  long mrow = (long)blockIdx.x * 128;                  // global pos base
  int ob = blockIdx.y * 128;                           // out base

  f32x16 zero16 = {0,0,0,0,0,0,0,0,0,0,0,0,0,0,0,0};
  f32x16 acc[3][2][2];
#pragma unroll
  for (int m = 0; m < 3; ++m)
#pragma unroll
    for (int p = 0; p < 2; ++p)
#pragma unroll
      for (int q = 0; q < 2; ++q) acc[m][p][q] = zero16;

  const u16* Ab = ht + mrow * 256;

  for (int step = 0; step < 8; ++step) {
    int k0 = step * 32;
    __syncthreads();                                   // prev frag reads done
    stage_gran<128, 256>(as2, Ab, k0, tid);
    stage_gran<128, 256>(bs2[0], wbf + (long)ob * 256, k0, tid);
    stage_gran<128, 256>(bs2[1], wbf + 65536 + (long)ob * 256, k0, tid);
    stage_gran<128, 256>(bs2[2], wbf + 131072 + (long)ob * 256, k0, tid);
    __syncthreads();                                   // stage complete

#pragma unroll
    for (int ks = 0; ks < 2; ++ks) {
      int kg = (2 * ks + h) * 128;
      bf16x8 a0 = *(const bf16x8*)(as2 + (long)(kg + wp * 64 + lr) * 8);
      bf16x8 a1 = *(const bf16x8*)(as2 + (long)(kg + wp * 64 + 32 + lr) * 8);
      __builtin_amdgcn_s_setprio(1);
#pragma unroll
      for (int m = 0; m < 3; ++m) {
        bf16x8 b0 = *(const bf16x8*)(bs2[m] + (long)(kg + wo * 64 + lr) * 8);
        bf16x8 b1 = *(const bf16x8*)(bs2[m] + (long)(kg + wo * 64 + 32 + lr) * 8);
        acc[m][0][0] = mfma32(a0, b0, acc[m][0][0]);
        acc[m][0][1] = mfma32(a0, b1, acc[m][0][1]);
        acc[m][1][0] = mfma32(a1, b0, acc[m][1][0]);
        acc[m][1][1] = mfma32(a1, b1, acc[m][1][1]);
      }
      __builtin_amdgcn_s_setprio(0);
    }
  }

  const float QSC = 0.0625f * 1.44269504f;   // C^-0.5 * log2(e), folded into q
  long b_ = mrow >> 12;
  int posb = (int)(mrow & 4095);
#pragma unroll
  for (int p = 0; p < 2; ++p)
#pragma unroll
    for (int q = 0; q < 2; ++q) {
      int o = ob + wo * 64 + q * 32 + lr;
      float bqv = bq[o], bkv = bk[o], bvv = bv[o];
      int posl0 = posb + wp * 64 + p * 32;             // 32-aligned
      int jt = posl0 >> 5;
      long tbase = b_ * 1048576 + (long)jt * 8192;
      long kbase = tbase + (o >> 3) * 256 + (o & 7);
      long vbase = tbase + (long)o * 8;
      long qrow0 = (mrow + wp * 64 + p * 32) * 256 + o;
#pragma unroll
      for (int quad = 0; quad < 4; ++quad) {
        __align__(8) u16 v4[4];
#pragma unroll
        for (int e = 0; e < 4; ++e) {
          int rloc = 8 * quad + 4 * h + e;             // 0..31
          float vq = acc[0][p][q][4 * quad + e];
          float vk = acc[1][p][q][4 * quad + e];
          float vv = acc[2][p][q][4 * quad + e];
          qtb[qrow0 + (long)rloc * 256] = f2bf((vq + bqv) * QSC);
          ktb[kbase + rloc * 8] = f2bf(vk + bkv);
          v4[e] = f2bf(vv + bvv);
        }
        int r0 = 8 * quad + 4 * h;
        *(uint2*)(vcb + vbase + ((r0 >> 3) & 3) * 2048 + (r0 & 7)) = *(uint2*)v4;
      }
    }
}

// ---------------- proj GEMM + residual (32x32 MFMA): out[b][o][pos] fp32 ----------------
// 512 blocks: b = bid&7 (XCD-aligned), pt = bid>>3 (64-pos tile). 4 waves = 4 o-subs.
// D rows = o (A=w frag), cols = pos (B=attn frag).
__global__ __launch_bounds__(256) void gemm_proj(
    const u16* __restrict__ Wp, const u16* __restrict__ ao,
    float* __restrict__ outp, const float* __restrict__ bias,
    const float* __restrict__ resid) {
  __shared__ __align__(16) u16 ws2[4 * 256 * 8];   // W [kh][o][8], 16KB
  __shared__ __align__(16) u16 aos[4 * 64 * 8];    // AO [kh][pos][8], 4KB

  int tid = threadIdx.x;
  int lane = tid & 63;
  int h = lane >> 5, lr = lane & 31;
  int wo = tid >> 6;
  long b = blockIdx.x & 7;
  int pos0 = (blockIdx.x >> 3) * 64;
  const u16* aob = ao + (b * 4096 + pos0) * 256;

  f32x16 zero16 = {0,0,0,0,0,0,0,0,0,0,0,0,0,0,0,0};
  f32x16 acc[2][2];                 // [p: o-sub 32][q: pos-sub 32]
#pragma unroll
  for (int p = 0; p < 2; ++p)
#pragma unroll
    for (int q = 0; q < 2; ++q) acc[p][q] = zero16;

  for (int step = 0; step < 8; ++step) {
    int k0 = step * 32;
    __syncthreads();
    stage_gran<256, 256>(ws2, Wp, k0, tid);
    stage_gran<64, 256>(aos, aob, k0, tid);
    __syncthreads();

#pragma unroll
    for (int ks = 0; ks < 2; ++ks) {
      int kgw = (2 * ks + h) * 256;
      int kga = (2 * ks + h) * 64;
      bf16x8 w0 = *(const bf16x8*)(ws2 + (long)(kgw + wo * 64 + lr) * 8);
      bf16x8 w1 = *(const bf16x8*)(ws2 + (long)(kgw + wo * 64 + 32 + lr) * 8);
      bf16x8 o0 = *(const bf16x8*)(aos + (long)(kga + lr) * 8);
      bf16x8 o1 = *(const bf16x8*)(aos + (long)(kga + 32 + lr) * 8);
      __builtin_amdgcn_s_setprio(1);
      acc[0][0] = mfma32(w0, o0, acc[0][0]);
      acc[0][1] = mfma32(w0, o1, acc[0][1]);
      acc[1][0] = mfma32(w1, o0, acc[1][0]);
      acc[1][1] = mfma32(w1, o1, acc[1][1]);
      __builtin_amdgcn_s_setprio(0);
    }
  }

#pragma unroll
  for (int p = 0; p < 2; ++p)
#pragma unroll
    for (int q = 0; q < 2; ++q) {
      int pos = pos0 + q * 32 + lr;
#pragma unroll
      for (int quad = 0; quad < 4; ++quad)
#pragma unroll
        for (int e = 0; e < 4; ++e) {
          int o = wo * 64 + p * 32 + 8 * quad + 4 * h + e;
          long addr = b * 1048576 + (long)o * 4096 + pos;
          outp[addr] = acc[p][q][4 * quad + e] + bias[o] + resid[addr];
        }
    }
}

// ---------------- flash attention: block-level j-split, full-c waves ----------------
// 1024 blocks: b = bid&7 (XCD-aligned), jhalf = (bid>>3)&1, itile = bid>>4.
// 128 thr = 2 waves (rg), 32 q-rows each, lane owns one q-row (swapped QK^T).
// Full c (acc 8 x f32x16 = 128 AGPR), single softmax copy. KVBLK=32 single-buffered
// (33KB LDS -> 4 independent blocks/CU; 2048 waves = 2/SIMD; cross-block overlap).
// Outputs: UNNORMALIZED bf16 partial O + per-row (m, lsum); merged by attn_merge.
__global__ __launch_bounds__(128, 2) void attn_flash(
    const u16* __restrict__ qt, const u16* __restrict__ kgp,
    const u16* __restrict__ vgp, u16* __restrict__ part0, u16* __restrict__ part1,
    float2* __restrict__ ml0, float2* __restrict__ ml1) {
  __shared__ __align__(16) u16 ksT[8192];   // [cg 32][j 32][8] = 16KB
  __shared__ __align__(16) u16 vsT[8192];   // [g 4][c 256][8] = 16KB
  __shared__ float fws[64];                 // [wave][32] broadcast scratch

  int tid = threadIdx.x;
  int lane = tid & 63;
  int h = lane >> 5, lr = lane & 31;
  int rg = tid >> 6;
  int bid = blockIdx.x;
  long b = bid & 7;
  int jhalf = (bid >> 3) & 1;
  int i0 = (bid >> 4) * 64;

  const u16* kb = kgp + b * 1048576 + (long)(jhalf * 64) * 8192;
  const u16* vb = vgp + b * 1048576 + (long)(jhalf * 64) * 8192;
  float* fw = fws + rg * 32;

  // Q: lane owns q-row (i0 + rg*32 + lr); frag kk holds c = kk*16 + 8h + e
  const u16* qrow = qt + ((b * 4096 + i0 + rg * 32 + lr) << 8) + h * 8;
  bf16x8 qreg[16];
#pragma unroll
  for (int kk = 0; kk < 16; ++kk)
    qreg[kk] = *(const bf16x8*)(qrow + kk * 16);

  f32x16 zero16 = {0,0,0,0,0,0,0,0,0,0,0,0,0,0,0,0};
  f32x16 acc[8];                 // O[row pattern][c = ct*32 + lr]
#pragma unroll
  for (int ct = 0; ct < 8; ++ct) acc[ct] = zero16;
  float mrun = -3e38f, lsum = 0.f;

  for (int t = 0; t < 64; ++t) {
    __syncthreads();                                   // prev compute done
    stage_lin<8, 128>(ksT, kb + (long)t * 8192, tid);
    stage_lin<8, 128>(vsT, vb + (long)t * 8192, tid);
    __syncthreads();                                   // stage complete

    // S^T = K * Q (log2 units): D col = lane&31 = own q-row, D row = j
    f32x16 sacc = zero16;
    __builtin_amdgcn_s_setprio(1);
#pragma unroll
    for (int kk = 0; kk < 16; ++kk) {
      bf16x8 kf = *(const bf16x8*)(ksT + ((2 * kk + h) * 32 + lr) * 8);
      sacc = mfma32(kf, qreg[kk], sacc);
    }
    __builtin_amdgcn_s_setprio(0);

    // row max: pairwise tree over 16 regs + xor-32 (partner has other 16 j's)
    float m0 = fmaxf(fmaxf(sacc[0], sacc[1]), fmaxf(sacc[2], sacc[3]));
    float m1 = fmaxf(fmaxf(sacc[4], sacc[5]), fmaxf(sacc[6], sacc[7]));
    float m2 = fmaxf(fmaxf(sacc[8], sacc[9]), fmaxf(sacc[10], sacc[11]));
    float m3 = fmaxf(fmaxf(sacc[12], sacc[13]), fmaxf(sacc[14], sacc[15]));
    float mloc = fmaxf(fmaxf(m0, m1), fmaxf(m2, m3));
    mloc = fmaxf(mloc, __shfl_xor(mloc, 32));

    // defer-max: rescale only when max grew by > 8 (log2 units)
    if (!__all(mloc - mrun <= 8.f)) {
      float mnew = fmaxf(mrun, mloc);
      float al = exp2f(mrun - mnew);
      mrun = mnew;
      lsum *= al;
      if (h == 0) fw[lr] = al;
      asm volatile("s_waitcnt lgkmcnt(0)" ::: "memory");
      f32x4 fq0 = *(const f32x4*)&fw[4 * h];
      f32x4 fq1 = *(const f32x4*)&fw[8 + 4 * h];
      f32x4 fq2 = *(const f32x4*)&fw[16 + 4 * h];
      f32x4 fq3 = *(const f32x4*)&fw[24 + 4 * h];
      f32x16 alv;
#pragma unroll
      for (int e = 0; e < 4; ++e) {
        alv[e] = fq0[e]; alv[4 + e] = fq1[e]; alv[8 + e] = fq2[e]; alv[12 + e] = fq3[e];
      }
#pragma unroll
      for (int ct = 0; ct < 8; ++ct) acc[ct] *= alv;
    }

    // P = exp2(S - m); pack bf16 pairs via v_cvt_pk_bf16_f32 (1 instr / pair)
    u32 u[8];
#pragma unroll
    for (int m = 0; m < 8; ++m) {
      float p0 = exp2f(sacc[2 * m] - mrun);
      float p1 = exp2f(sacc[2 * m + 1] - mrun);
      lsum += p0 + p1;
      asm volatile("v_cvt_pk_bf16_f32 %0, %1, %2" : "=v"(u[m]) : "v"(p0), "v"(p1));
    }
    // half-exchange with lane^32 to assemble PV A-fragments
    u32 rv[4];
#pragma unroll
    for (int kt2 = 0; kt2 < 2; ++kt2)
#pragma unroll
      for (int idx = 0; idx < 2; ++idx) {
        u32 send = h ? u[4 * kt2 + idx] : u[4 * kt2 + 2 + idx];
        rv[kt2 * 2 + idx] = (u32)__shfl_xor((int)send, 32);
      }
    union { u32 wd[4]; bf16x8 v; } pf[2];
#pragma unroll
    for (int kt2 = 0; kt2 < 2; ++kt2) {
      pf[kt2].wd[0] = h ? rv[kt2 * 2] : u[4 * kt2];
      pf[kt2].wd[1] = h ? rv[kt2 * 2 + 1] : u[4 * kt2 + 1];
      pf[kt2].wd[2] = h ? u[4 * kt2 + 2] : rv[kt2 * 2];
      pf[kt2].wd[3] = h ? u[4 * kt2 + 3] : rv[kt2 * 2 + 1];
    }

    // PV full-c: O[i][c] += P[i][j] * V[c][j]
    __builtin_amdgcn_s_setprio(1);
#pragma unroll
    for (int ct = 0; ct < 8; ++ct) {
      int c = ct * 32 + lr;
      bf16x8 vf0 = *(const bf16x8*)(vsT + ((long)h * 256 + c) * 8);
      bf16x8 vf1 = *(const bf16x8*)(vsT + ((long)(2 + h) * 256 + c) * 8);
      acc[ct] = mfma32(pf[0].v, vf0, acc[ct]);
      acc[ct] = mfma32(pf[1].v, vf1, acc[ct]);
    }
    __builtin_amdgcn_s_setprio(0);
  }

  // epilogue: store UNNORMALIZED partial O (bf16) + per-row (m, lsum)
  lsum += __shfl_xor(lsum, 32);
  u16* pout = jhalf ? part1 : part0;
  float2* mlo = jhalf ? ml1 : ml0;
  if (h == 0)
    mlo[b * 4096 + i0 + rg * 32 + lr] = make_float2(mrun, lsum);
  u16* ob = pout + ((b * 4096 + i0 + rg * 32) << 8);
#pragma unroll
  for (int ct = 0; ct < 8; ++ct) {
    int c = ct * 32 + lr;
#pragma unroll
    for (int q = 0; q < 4; ++q)
#pragma unroll
      for (int e = 0; e < 4; ++e) {
        int i = 8 * q + 4 * h + e;
        ob[(long)i * 256 + c] = f2bf(acc[ct][4 * q + e]);
      }
  }
}

// ---------------- merge the two j-half partials ----------------
__global__ __launch_bounds__(256) void attn_merge(
    const u16* __restrict__ p0, const u16* __restrict__ p1,
    const float2* __restrict__ ml0, const float2* __restrict__ ml1,
    u16* __restrict__ out) {
  int tid = threadIdx.x;
  int row = blockIdx.x * 16 + (tid >> 4);
  int cs = (tid & 15) * 16;
  float2 a = ml0[row], c = ml1[row];
  float M = fmaxf(a.x, c.x);
  float w0 = exp2f(a.x - M), w1 = exp2f(c.x - M);
  float rl = 1.0f / (w0 * a.y + w1 * c.y);
  float f0 = w0 * rl, f1 = w1 * rl;

  long base = (long)row * 256 + cs;
  bf16x8 a0 = *(const bf16x8*)(p0 + base);
  bf16x8 a1 = *(const bf16x8*)(p0 + base + 8);
  bf16x8 c0 = *(const bf16x8*)(p1 + base);
  bf16x8 c1 = *(const bf16x8*)(p1 + base + 8);
  __align__(16) u16 o[16];
#pragma unroll
  for (int k = 0; k < 8; ++k) {
    o[k]     = f2bf(f0 * (float)a0[k] + f1 * (float)c0[k]);
    o[k + 8] = f2bf(f0 * (float)a1[k] + f1 * (float)c1[k]);
  }
  *(uint4*)(out + base) = ((uint4*)o)[0];
  *(uint4*)(out + base + 8) = ((uint4*)o)[1];
}

// ---------------- launcher ----------------
extern "C" void kernel_launch(void* const* d_in, const int* in_sizes, int n_in,
                              void* d_out, int out_size, void* d_ws, size_t ws_size,
                              hipStream_t stream) {
  const float* x     = (const float*)d_in[0];
  const float* gamma = (const float*)d_in[1];
  const float* beta  = (const float*)d_in[2];
  const float* wq = (const float*)d_in[3];
  const float* bq = (const float*)d_in[4];
  const float* wk = (const float*)d_in[5];
  const float* bk = (const float*)d_in[6];
  const float* wv = (const float*)d_in[7];
  const float* bv = (const float*)d_in[8];
  const float* wp = (const float*)d_in[9];
  const float* bp = (const float*)d_in[10];

  char* ws = (char*)d_ws;
  const long SZ = 16777216;            // one [B][N][C] bf16 tensor
  u16* ht  = (u16*)(ws);
  u16* qtb = (u16*)(ws + SZ);
  u16* ktb = (u16*)(ws + 2 * SZ);      // granule-planar K
  u16* vcb = (u16*)(ws + 3 * SZ);      // granule-planar V
  u16* wbf = (u16*)(ws + 4 * SZ);      // wq|wk|wv|wp, 65536 u16 each (512KB)
  u16* part0 = ht;                     // h dead after QKV
  // d_out (32MB) doubles as scratch: partial1 (16MB) + ml0/ml1 (512KB).
  u16* part1 = (u16*)d_out;
  float2* ml0 = (float2*)((char*)d_out + SZ);
  float2* ml1 = (float2*)((char*)d_out + SZ + 262144);

  convert_w<<<1024, 256, 0, stream>>>(wq, wk, wv, wp, wbf);
  gn_kernel<<<128, 256, 0, stream>>>(x, gamma, beta, ht);

  dim3 gq(256, 2, 1);   // 128-pos x 128-out tiles
  gemm_qkv<<<gq, 256, 0, stream>>>(ht, wbf, qtb, ktb, vcb, bq, bk, bv);

  attn_flash<<<1024, 128, 0, stream>>>(qtb, ktb, vcb, part0, part1, ml0, ml1);

  // merged attn output -> qtb (q dead after attn); proj reads it
  attn_merge<<<2048, 256, 0, stream>>>(part0, part1, ml0, ml1, qtb);

  dim3 gp(512, 1, 1);
  gemm_proj<<<gp, 256, 0, stream>>>(wbf + 3 * 65536, qtb, (float*)d_out, bp, x);
}

// Round 11
// 312.153 us; speedup vs baseline: 1.3788x; 1.0694x over previous
//
#include <hip/hip_runtime.h>
#include <hip/hip_bf16.h>

// AttnBlock2d: GN -> q/k/v 1x1conv -> softmax(q^T k / sqrt(C)) -> v@alpha -> proj -> +x
// B=8, C=256, H*W=4096. bf16 MFMA, fp32 accum.
// R11: attn loop rebuilt on T4 counted-vmcnt double-buffering: raw s_barrier +
// s_waitcnt vmcnt(8) keeps the K/V prefetch in flight ACROSS the barrier (the
// __syncthreads vmcnt(0) drain was exposing full stage latency every iter).
// Blocks widened to 4 waves / 128 q-rows (stage writes halve; 2 blocks/CU x 4
// waves = 8 waves/CU unchanged; regs identical to R9 -> no spill).
// gn/qkv/merge/proj unchanged from R10.

typedef unsigned int u32;
typedef unsigned short u16;
typedef __bf16 bf16x8 __attribute__((ext_vector_type(8)));
typedef float f32x4 __attribute__((ext_vector_type(4)));
typedef float f32x16 __attribute__((ext_vector_type(16)));

#define GAS __attribute__((address_space(1)))
#define LAS __attribute__((address_space(3)))

__device__ __forceinline__ u16 f2bf(float f) {
  union { float f; u32 u; } v; v.f = f;
  return (u16)((v.u + 0x7fffu + ((v.u >> 16) & 1u)) >> 16);
}

__device__ __forceinline__ f32x16 mfma32(bf16x8 a, bf16x8 b, f32x16 c) {
  return __builtin_amdgcn_mfma_f32_32x32x16_bf16(a, b, c, 0, 0, 0);
}

// Stage a fully-contiguous region: linear global -> linear LDS, coalesced.
template<int ITERS, int NT>
__device__ __forceinline__ void stage_lin(u16* lds, const u16* g, int tid) {
#pragma unroll
  for (int it = 0; it < ITERS; ++it) {
    int idx = it * NT + tid;
    const u16* src = g + (long)idx * 8;
    u16* dst = lds + (long)(idx & ~63) * 8;
    __builtin_amdgcn_global_load_lds((const GAS u32*)src, (LAS u32*)dst, 16, 0, 0);
  }
}

// Stage a [ROWS][256] row-major bf16 matrix slice (cols k0..k0+32) into
// granule-planar LDS [kh=4][ROWS][8]: per-lane global src, linear LDS dst.
template<int ROWS, int NT>
__device__ __forceinline__ void stage_gran(u16* lds, const u16* g, int k0, int tid) {
  constexpr int ITERS = 4 * ROWS / NT;
#pragma unroll
  for (int it = 0; it < ITERS; ++it) {
    int gi = it * NT + tid;
    int row = gi & (ROWS - 1);
    int kh = gi / ROWS;
    const u16* src = g + (long)row * 256 + k0 + kh * 8;
    u16* dst = lds + (long)(gi & ~63) * 8;
    __builtin_amdgcn_global_load_lds((const GAS u32*)src, (LAS u32*)dst, 16, 0, 0);
  }
}

// ---------------- weight fp32 -> bf16 ----------------
__global__ __launch_bounds__(256) void convert_w(
    const float* __restrict__ w0, const float* __restrict__ w1,
    const float* __restrict__ w2, const float* __restrict__ w3,
    u16* __restrict__ out) {
  int i = blockIdx.x * 256 + threadIdx.x;
  int seg = i >> 16, idx = i & 65535;
  const float* w = seg == 0 ? w0 : seg == 1 ? w1 : seg == 2 ? w2 : w3;
  out[i] = f2bf(w[idx]);
}

// ---------------- GroupNorm: x [B][C][N] fp32 -> h_t [B][N][C] bf16 ----------------
__global__ __launch_bounds__(256) void gn_kernel(
    const float* __restrict__ x, const float* __restrict__ gamma,
    const float* __restrict__ beta, u16* __restrict__ ht) {
  int tid = threadIdx.x;
  int b = blockIdx.x >> 4;
  int grp = blockIdx.x & 15;
  const float* xg = x + ((long)b * 256 + grp * 16) * 4096;

  float s = 0.f, ss = 0.f;
  const float4* x4 = (const float4*)xg;
#pragma unroll 4
  for (int it = 0; it < 64; ++it) {
    float4 v = x4[it * 256 + tid];
    s += v.x + v.y + v.z + v.w;
    ss += v.x * v.x + v.y * v.y + v.z * v.z + v.w * v.w;
  }
#pragma unroll
  for (int d = 1; d < 64; d <<= 1) {
    s += __shfl_xor(s, d);
    ss += __shfl_xor(ss, d);
  }
  __shared__ float red[10];
  int lane = tid & 63, wave = tid >> 6;
  if (lane == 0) { red[wave] = s; red[4 + wave] = ss; }
  __syncthreads();
  if (tid == 0) {
    float S = red[0] + red[1] + red[2] + red[3];
    float SS = red[4] + red[5] + red[6] + red[7];
    float mean = S * (1.f / 65536.f);
    float var = SS * (1.f / 65536.f) - mean * mean;
    red[8] = mean;
    red[9] = rsqrtf(var + 1e-6f);
  }
  __syncthreads();
  float mean = red[8], rstd = red[9];

  float a[16], bb[16];
#pragma unroll
  for (int c = 0; c < 16; ++c) {
    float gm = gamma[grp * 16 + c];
    float bt = beta[grp * 16 + c];
    a[c] = gm * rstd;
    bb[c] = bt - mean * a[c];
  }
  u16* hb = ht + (long)b * 4096 * 256 + grp * 16;
  for (int it = 0; it < 16; ++it) {
    int n = it * 256 + tid;
    __align__(16) u16 tmp[16];
#pragma unroll
    for (int c = 0; c < 16; ++c)
      tmp[c] = f2bf(xg[(long)c * 4096 + n] * a[c] + bb[c]);
    u16* dst = hb + (long)n * 256;
    ((uint4*)dst)[0] = ((uint4*)tmp)[0];
    ((uint4*)dst)[1] = ((uint4*)tmp)[1];
  }
}

// ---------------- fused QKV GEMM (32x32 MFMA, granule-planar LDS) ----------------
__global__ __launch_bounds__(256, 2) void gemm_qkv(
    const u16* __restrict__ ht, const u16* __restrict__ wbf,
    u16* __restrict__ qtb, u16* __restrict__ ktb, u16* __restrict__ vcb,
    const float* __restrict__ bq, const float* __restrict__ bk,
    const float* __restrict__ bv) {
  __shared__ __align__(16) u16 as2[4 * 128 * 8];      // A [kh][pos][8], 8KB
  __shared__ __align__(16) u16 bs2[3][4 * 128 * 8];   // B per matrix, 24KB

  int tid = threadIdx.x;
  int lane = tid & 63;
  int h = lane >> 5, lr = lane & 31;
  int wave = tid >> 6;
  int wp = wave >> 1, wo = wave & 1;
  long mrow = (long)blockIdx.x * 128;                  // global pos base
  int ob = blockIdx.y * 128;                           // out base

  f32x16 zero16 = {0,0,0,0,0,0,0,0,0,0,0,0,0,0,0,0};
  f32x16 acc[3][2][2];
#pragma unroll
  for (int m = 0; m < 3; ++m)
#pragma unroll
    for (int p = 0; p < 2; ++p)
#pragma unroll
      for (int q = 0; q < 2; ++q) acc[m][p][q] = zero16;

  const u16* Ab = ht + mrow * 256;

  for (int step = 0; step < 8; ++step) {
    int k0 = step * 32;
    __syncthreads();                                   // prev frag reads done
    stage_gran<128, 256>(as2, Ab, k0, tid);
    stage_gran<128, 256>(bs2[0], wbf + (long)ob * 256, k0, tid);
    stage_gran<128, 256>(bs2[1], wbf + 65536 + (long)ob * 256, k0, tid);
    stage_gran<128, 256>(bs2[2], wbf + 131072 + (long)ob * 256, k0, tid);
    __syncthreads();                                   // stage complete

#pragma unroll
    for (int ks = 0; ks < 2; ++ks) {
      int kg = (2 * ks + h) * 128;
      bf16x8 a0 = *(const bf16x8*)(as2 + (long)(kg + wp * 64 + lr) * 8);
      bf16x8 a1 = *(const bf16x8*)(as2 + (long)(kg + wp * 64 + 32 + lr) * 8);
      __builtin_amdgcn_s_setprio(1);
#pragma unroll
      for (int m = 0; m < 3; ++m) {
        bf16x8 b0 = *(const bf16x8*)(bs2[m] + (long)(kg + wo * 64 + lr) * 8);
        bf16x8 b1 = *(const bf16x8*)(bs2[m] + (long)(kg + wo * 64 + 32 + lr) * 8);
        acc[m][0][0] = mfma32(a0, b0, acc[m][0][0]);
        acc[m][0][1] = mfma32(a0, b1, acc[m][0][1]);
        acc[m][1][0] = mfma32(a1, b0, acc[m][1][0]);
        acc[m][1][1] = mfma32(a1, b1, acc[m][1][1]);
      }
      __builtin_amdgcn_s_setprio(0);
    }
  }

  const float QSC = 0.0625f * 1.44269504f;   // C^-0.5 * log2(e), folded into q
  long b_ = mrow >> 12;
  int posb = (int)(mrow & 4095);
#pragma unroll
  for (int p = 0; p < 2; ++p)
#pragma unroll
    for (int q = 0; q < 2; ++q) {
      int o = ob + wo * 64 + q * 32 + lr;
      float bqv = bq[o], bkv = bk[o], bvv = bv[o];
      int posl0 = posb + wp * 64 + p * 32;             // 32-aligned
      int jt = posl0 >> 5;
      long tbase = b_ * 1048576 + (long)jt * 8192;
      long kbase = tbase + (o >> 3) * 256 + (o & 7);
      long vbase = tbase + (long)o * 8;
      long qrow0 = (mrow + wp * 64 + p * 32) * 256 + o;
#pragma unroll
      for (int quad = 0; quad < 4; ++quad) {
        __align__(8) u16 v4[4];
#pragma unroll
        for (int e = 0; e < 4; ++e) {
          int rloc = 8 * quad + 4 * h + e;             // 0..31
          float vq = acc[0][p][q][4 * quad + e];
          float vk = acc[1][p][q][4 * quad + e];
          float vv = acc[2][p][q][4 * quad + e];
          qtb[qrow0 + (long)rloc * 256] = f2bf((vq + bqv) * QSC);
          ktb[kbase + rloc * 8] = f2bf(vk + bkv);
          v4[e] = f2bf(vv + bvv);
        }
        int r0 = 8 * quad + 4 * h;
        *(uint2*)(vcb + vbase + ((r0 >> 3) & 3) * 2048 + (r0 & 7)) = *(uint2*)v4;
      }
    }
}

// ---------------- proj GEMM + residual (32x32 MFMA): out[b][o][pos] fp32 ----------------
__global__ __launch_bounds__(256) void gemm_proj(
    const u16* __restrict__ Wp, const u16* __restrict__ ao,
    float* __restrict__ outp, const float* __restrict__ bias,
    const float* __restrict__ resid) {
  __shared__ __align__(16) u16 ws2[4 * 256 * 8];   // W [kh][o][8], 16KB
  __shared__ __align__(16) u16 aos[4 * 64 * 8];    // AO [kh][pos][8], 4KB

  int tid = threadIdx.x;
  int lane = tid & 63;
  int h = lane >> 5, lr = lane & 31;
  int wo = tid >> 6;
  long b = blockIdx.x & 7;
  int pos0 = (blockIdx.x >> 3) * 64;
  const u16* aob = ao + (b * 4096 + pos0) * 256;

  f32x16 zero16 = {0,0,0,0,0,0,0,0,0,0,0,0,0,0,0,0};
  f32x16 acc[2][2];                 // [p: o-sub 32][q: pos-sub 32]
#pragma unroll
  for (int p = 0; p < 2; ++p)
#pragma unroll
    for (int q = 0; q < 2; ++q) acc[p][q] = zero16;

  for (int step = 0; step < 8; ++step) {
    int k0 = step * 32;
    __syncthreads();
    stage_gran<256, 256>(ws2, Wp, k0, tid);
    stage_gran<64, 256>(aos, aob, k0, tid);
    __syncthreads();

#pragma unroll
    for (int ks = 0; ks < 2; ++ks) {
      int kgw = (2 * ks + h) * 256;
      int kga = (2 * ks + h) * 64;
      bf16x8 w0 = *(const bf16x8*)(ws2 + (long)(kgw + wo * 64 + lr) * 8);
      bf16x8 w1 = *(const bf16x8*)(ws2 + (long)(kgw + wo * 64 + 32 + lr) * 8);
      bf16x8 o0 = *(const bf16x8*)(aos + (long)(kga + lr) * 8);
      bf16x8 o1 = *(const bf16x8*)(aos + (long)(kga + 32 + lr) * 8);
      __builtin_amdgcn_s_setprio(1);
      acc[0][0] = mfma32(w0, o0, acc[0][0]);
      acc[0][1] = mfma32(w0, o1, acc[0][1]);
      acc[1][0] = mfma32(w1, o0, acc[1][0]);
      acc[1][1] = mfma32(w1, o1, acc[1][1]);
      __builtin_amdgcn_s_setprio(0);
    }
  }

#pragma unroll
  for (int p = 0; p < 2; ++p)
#pragma unroll
    for (int q = 0; q < 2; ++q) {
      int pos = pos0 + q * 32 + lr;
#pragma unroll
      for (int quad = 0; quad < 4; ++quad)
#pragma unroll
        for (int e = 0; e < 4; ++e) {
          int o = wo * 64 + p * 32 + 8 * quad + 4 * h + e;
          long addr = b * 1048576 + (long)o * 4096 + pos;
          outp[addr] = acc[p][q][4 * quad + e] + bias[o] + resid[addr];
        }
    }
}

// ---------------- flash attention: j-split blocks, 4 waves, counted-vmcnt dbuf ----------------
// 512 blocks: b = bid&7 (XCD-aligned), jhalf = (bid>>3)&1, itile = bid>>4 (128 rows).
// 256 thr = 4 waves (rg = wave), 32 q-rows each, lane owns one q-row (swapped QK^T).
// K/V double-buffered (64KB); loop keeps 8 prefetch glds in flight ACROSS raw
// s_barriers via s_waitcnt vmcnt(8) (T4) -- no vmcnt(0) drain, stage latency hides
// under compute. Outputs unnormalized bf16 partials + (m,l); merged by attn_merge.
__global__ __launch_bounds__(256, 2) void attn_flash(
    const u16* __restrict__ qt, const u16* __restrict__ kgp,
    const u16* __restrict__ vgp, u16* __restrict__ part0, u16* __restrict__ part1,
    float2* __restrict__ ml0, float2* __restrict__ ml1) {
  __shared__ __align__(16) u16 ksT[2 * 8192];   // [buf][cg 32][j 32][8] = 2x16KB
  __shared__ __align__(16) u16 vsT[2 * 8192];   // [buf][g 4][c 256][8] = 2x16KB
  __shared__ float fws[128];                    // [wave][32] broadcast scratch

  int tid = threadIdx.x;
  int lane = tid & 63;
  int h = lane >> 5, lr = lane & 31;
  int rg = tid >> 6;
  int bid = blockIdx.x;
  long b = bid & 7;
  int jhalf = (bid >> 3) & 1;
  int i0 = (bid >> 4) * 128;

  const u16* kb = kgp + b * 1048576 + (long)(jhalf * 64) * 8192;
  const u16* vb = vgp + b * 1048576 + (long)(jhalf * 64) * 8192;
  float* fw = fws + rg * 32;

  // Q: lane owns q-row (i0 + rg*32 + lr); frag kk holds c = kk*16 + 8h + e
  const u16* qrow = qt + ((b * 4096 + i0 + rg * 32 + lr) << 8) + h * 8;
  bf16x8 qreg[16];
#pragma unroll
  for (int kk = 0; kk < 16; ++kk)
    qreg[kk] = *(const bf16x8*)(qrow + kk * 16);

  f32x16 zero16 = {0,0,0,0,0,0,0,0,0,0,0,0,0,0,0,0};
  f32x16 acc[8];                 // O[row pattern][c = ct*32 + lr]
#pragma unroll
  for (int ct = 0; ct < 8; ++ct) acc[ct] = zero16;
  float mrun = -3e38f, lsum = 0.f;

  // prologue: stage tile 0 into buf 0 (4 K-ops + 4 V-ops per thread)
  stage_lin<4, 256>(ksT, kb, tid);
  stage_lin<4, 256>(vsT, vb, tid);

  for (int t = 0; t < 64; ++t) {
    int cur = t & 1, nxt = cur ^ 1;
    // barrier 1: all waves done READING buf[nxt] (from iter t-1); ok to overwrite.
    __builtin_amdgcn_s_barrier();
    __builtin_amdgcn_sched_barrier(0);
    if (t < 63) {
      stage_lin<4, 256>(ksT + nxt * 8192, kb + (long)(t + 1) * 8192, tid);
      stage_lin<4, 256>(vsT + nxt * 8192, vb + (long)(t + 1) * 8192, tid);
    }
    __builtin_amdgcn_sched_barrier(0);
    // wait stage(t) complete: allow the 8 just-issued stage(t+1) ops to remain.
    asm volatile("s_waitcnt vmcnt(8)" ::: "memory");
    __builtin_amdgcn_sched_barrier(0);
    // barrier 2: every wave has verified stage(t); buf[cur] globally ready.
    __builtin_amdgcn_s_barrier();
    __builtin_amdgcn_sched_barrier(0);

    const u16* ksl = ksT + cur * 8192;
    const u16* vsl = vsT + cur * 8192;

    // S^T = K * Q (log2 units): D col = lane&31 = own q-row, D row = j
    f32x16 sacc = zero16;
    __builtin_amdgcn_s_setprio(1);
#pragma unroll
    for (int kk = 0; kk < 16; ++kk) {
      bf16x8 kf = *(const bf16x8*)(ksl + ((2 * kk + h) * 32 + lr) * 8);
      sacc = mfma32(kf, qreg[kk], sacc);
    }
    __builtin_amdgcn_s_setprio(0);

    // row max: pairwise tree over 16 regs + xor-32 (partner has other 16 j's)
    float m0 = fmaxf(fmaxf(sacc[0], sacc[1]), fmaxf(sacc[2], sacc[3]));
    float m1 = fmaxf(fmaxf(sacc[4], sacc[5]), fmaxf(sacc[6], sacc[7]));
    float m2 = fmaxf(fmaxf(sacc[8], sacc[9]), fmaxf(sacc[10], sacc[11]));
    float m3 = fmaxf(fmaxf(sacc[12], sacc[13]), fmaxf(sacc[14], sacc[15]));
    float mloc = fmaxf(fmaxf(m0, m1), fmaxf(m2, m3));
    mloc = fmaxf(mloc, __shfl_xor(mloc, 32));

    // defer-max: rescale only when max grew by > 8 (log2 units)
    if (!__all(mloc - mrun <= 8.f)) {
      float mnew = fmaxf(mrun, mloc);
      float al = exp2f(mrun - mnew);
      mrun = mnew;
      lsum *= al;
      if (h == 0) fw[lr] = al;
      asm volatile("s_waitcnt lgkmcnt(0)" ::: "memory");
      f32x4 fq0 = *(const f32x4*)&fw[4 * h];
      f32x4 fq1 = *(const f32x4*)&fw[8 + 4 * h];
      f32x4 fq2 = *(const f32x4*)&fw[16 + 4 * h];
      f32x4 fq3 = *(const f32x4*)&fw[24 + 4 * h];
      f32x16 alv;
#pragma unroll
      for (int e = 0; e < 4; ++e) {
        alv[e] = fq0[e]; alv[4 + e] = fq1[e]; alv[8 + e] = fq2[e]; alv[12 + e] = fq3[e];
      }
#pragma unroll
      for (int ct = 0; ct < 8; ++ct) acc[ct] *= alv;
    }

    // P = exp2(S - m); pack bf16 pairs via v_cvt_pk_bf16_f32 (1 instr / pair)
    u32 u[8];
#pragma unroll
    for (int m = 0; m < 8; ++m) {
      float p0 = exp2f(sacc[2 * m] - mrun);
      float p1 = exp2f(sacc[2 * m + 1] - mrun);
      lsum += p0 + p1;
      asm volatile("v_cvt_pk_bf16_f32 %0, %1, %2" : "=v"(u[m]) : "v"(p0), "v"(p1));
    }
    // half-exchange with lane^32 to assemble PV A-fragments
    u32 rv[4];
#pragma unroll
    for (int kt2 = 0; kt2 < 2; ++kt2)
#pragma unroll
      for (int idx = 0; idx < 2; ++idx) {
        u32 send = h ? u[4 * kt2 + idx] : u[4 * kt2 + 2 + idx];
        rv[kt2 * 2 + idx] = (u32)__shfl_xor((int)send, 32);
      }
    union { u32 wd[4]; bf16x8 v; } pf[2];
#pragma unroll
    for (int kt2 = 0; kt2 < 2; ++kt2) {
      pf[kt2].wd[0] = h ? rv[kt2 * 2] : u[4 * kt2];
      pf[kt2].wd[1] = h ? rv[kt2 * 2 + 1] : u[4 * kt2 + 1];
      pf[kt2].wd[2] = h ? u[4 * kt2 + 2] : rv[kt2 * 2];
      pf[kt2].wd[3] = h ? u[4 * kt2 + 3] : rv[kt2 * 2 + 1];
    }

    // PV full-c: O[i][c] += P[i][j] * V[c][j]
    __builtin_amdgcn_s_setprio(1);
#pragma unroll
    for (int ct = 0; ct < 8; ++ct) {
      int c = ct * 32 + lr;
      bf16x8 vf0 = *(const bf16x8*)(vsl + ((long)h * 256 + c) * 8);
      bf16x8 vf1 = *(const bf16x8*)(vsl + ((long)(2 + h) * 256 + c) * 8);
      acc[ct] = mfma32(pf[0].v, vf0, acc[ct]);
      acc[ct] = mfma32(pf[1].v, vf1, acc[ct]);
    }
    __builtin_amdgcn_s_setprio(0);
    __builtin_amdgcn_sched_barrier(0);
  }

  // epilogue: store UNNORMALIZED partial O (bf16) + per-row (m, lsum)
  lsum += __shfl_xor(lsum, 32);
  u16* pout = jhalf ? part1 : part0;
  float2* mlo = jhalf ? ml1 : ml0;
  if (h == 0)
    mlo[b * 4096 + i0 + rg * 32 + lr] = make_float2(mrun, lsum);
  u16* ob = pout + ((b * 4096 + i0 + rg * 32) << 8);
#pragma unroll
  for (int ct = 0; ct < 8; ++ct) {
    int c = ct * 32 + lr;
#pragma unroll
    for (int q = 0; q < 4; ++q)
#pragma unroll
      for (int e = 0; e < 4; ++e) {
        int i = 8 * q + 4 * h + e;
        ob[(long)i * 256 + c] = f2bf(acc[ct][4 * q + e]);
      }
  }
}

// ---------------- merge the two j-half partials ----------------
__global__ __launch_bounds__(256) void attn_merge(
    const u16* __restrict__ p0, const u16* __restrict__ p1,
    const float2* __restrict__ ml0, const float2* __restrict__ ml1,
    u16* __restrict__ out) {
  int tid = threadIdx.x;
  int row = blockIdx.x * 16 + (tid >> 4);
  int cs = (tid & 15) * 16;
  float2 a = ml0[row], c = ml1[row];
  float M = fmaxf(a.x, c.x);
  float w0 = exp2f(a.x - M), w1 = exp2f(c.x - M);
  float rl = 1.0f / (w0 * a.y + w1 * c.y);
  float f0 = w0 * rl, f1 = w1 * rl;

  long base = (long)row * 256 + cs;
  bf16x8 a0 = *(const bf16x8*)(p0 + base);
  bf16x8 a1 = *(const bf16x8*)(p0 + base + 8);
  bf16x8 c0 = *(const bf16x8*)(p1 + base);
  bf16x8 c1 = *(const bf16x8*)(p1 + base + 8);
  __align__(16) u16 o[16];
#pragma unroll
  for (int k = 0; k < 8; ++k) {
    o[k]     = f2bf(f0 * (float)a0[k] + f1 * (float)c0[k]);
    o[k + 8] = f2bf(f0 * (float)a1[k] + f1 * (float)c1[k]);
  }
  *(uint4*)(out + base) = ((uint4*)o)[0];
  *(uint4*)(out + base + 8) = ((uint4*)o)[1];
}

// ---------------- launcher ----------------
extern "C" void kernel_launch(void* const* d_in, const int* in_sizes, int n_in,
                              void* d_out, int out_size, void* d_ws, size_t ws_size,
                              hipStream_t stream) {
  const float* x     = (const float*)d_in[0];
  const float* gamma = (const float*)d_in[1];
  const float* beta  = (const float*)d_in[2];
  const float* wq = (const float*)d_in[3];
  const float* bq = (const float*)d_in[4];
  const float* wk = (const float*)d_in[5];
  const float* bk = (const float*)d_in[6];
  const float* wv = (const float*)d_in[7];
  const float* bv = (const float*)d_in[8];
  const float* wp = (const float*)d_in[9];
  const float* bp = (const float*)d_in[10];

  char* ws = (char*)d_ws;
  const long SZ = 16777216;            // one [B][N][C] bf16 tensor
  u16* ht  = (u16*)(ws);
  u16* qtb = (u16*)(ws + SZ);
  u16* ktb = (u16*)(ws + 2 * SZ);      // granule-planar K
  u16* vcb = (u16*)(ws + 3 * SZ);      // granule-planar V
  u16* wbf = (u16*)(ws + 4 * SZ);      // wq|wk|wv|wp, 65536 u16 each (512KB)
  u16* part0 = ht;                     // h dead after QKV
  // d_out (32MB) doubles as scratch: partial1 (16MB) + ml0/ml1 (512KB).
  u16* part1 = (u16*)d_out;
  float2* ml0 = (float2*)((char*)d_out + SZ);
  float2* ml1 = (float2*)((char*)d_out + SZ + 262144);

  convert_w<<<1024, 256, 0, stream>>>(wq, wk, wv, wp, wbf);
  gn_kernel<<<128, 256, 0, stream>>>(x, gamma, beta, ht);

  dim3 gq(256, 2, 1);   // 128-pos x 128-out tiles
  gemm_qkv<<<gq, 256, 0, stream>>>(ht, wbf, qtb, ktb, vcb, bq, bk, bv);

  attn_flash<<<512, 256, 0, stream>>>(qtb, ktb, vcb, part0, part1, ml0, ml1);

  // merged attn output -> qtb (q dead after attn); proj reads it
  attn_merge<<<2048, 256, 0, stream>>>(part0, part1, ml0, ml1, qtb);

  dim3 gp(512, 1, 1);
  gemm_proj<<<gp, 256, 0, stream>>>(wbf + 3 * 65536, qtb, (float*)d_out, bp, x);
}